// Round 3
// baseline (609.913 us; speedup 1.0000x reference)
//
#include <hip/hip_runtime.h>

// Problem constants (from reference)
constexpr int N_NODES = 100000;
constexpr int N_EDGES = 1600000;
constexpr int D = 64;          // D_IN == D_OUT == 64

// Bucketing: 64 consecutive dst nodes per bucket (one k_bucket block each).
constexpr int BSH    = 6;
constexpr int BN     = 1 << BSH;                              // 64
constexpr int NBUCK  = (N_NODES + BN - 1) / BN;               // 1563
constexpr int NN2    = NBUCK * BN;                            // 100032 (padded nodes)
constexpr int NCNTB  = 800;                                   // count blocks
constexpr int EPB2   = N_EDGES / NCNTB;                       // 2000 (exact)
constexpr int NCVT   = (N_NODES * D / 4) / 256;               // 6250 cvt blocks
constexpr int NPLACE = 1024;                                  // placement blocks

// ---------------------------------------------------------------------------
// Workspace layout (bytes). Total 26,833,920 <= 40,280,064 (verified avail).
// Single-level per-node counting sort: no bucket-level intermediates.
// ---------------------------------------------------------------------------
constexpr size_t OFF_NCNT    = 0;                              // NN2 ints
constexpr size_t OFF_NSTART  = 400384;                         // NN2+1 ints
constexpr size_t OFF_NCUR    = 800768;                         // NN2 ints
constexpr size_t OFF_W16     = 1201152;                        // 32 KB (hi+lo planes)
constexpr size_t OFF_FEAT16  = 1233920;                        // N_NODES*64 bf16
constexpr size_t OFF_ENT2    = OFF_FEAT16 + (size_t)N_NODES * D * 2;   // 14,033,920
constexpr size_t WS_NEEDED   = OFF_ENT2 + (size_t)N_EDGES * 8;         // 26,833,920

typedef short  bf16x8 __attribute__((ext_vector_type(8)));
typedef float  f32x4  __attribute__((ext_vector_type(4)));

__device__ __forceinline__ unsigned short f2bf(float f) {   // RNE f32 -> bf16
    unsigned u = __float_as_uint(f);
    u += 0x7fffu + ((u >> 16) & 1u);
    return (unsigned short)(u >> 16);
}

// Split 8 consecutive f32 into hi/lo bf16 fragments (hi = RNE(f), lo = RNE(f - hi)).
// Residual after the split is ~2^-16 relative: near-f32 via 3-product MFMA.
__device__ __forceinline__ void split8(float4 p0, float4 p1, bf16x8& hi, bf16x8& lo) {
    float f[8] = {p0.x, p0.y, p0.z, p0.w, p1.x, p1.y, p1.z, p1.w};
#pragma unroll
    for (int i = 0; i < 8; ++i) {
        const unsigned short h = f2bf(f[i]);
        const float hf = __uint_as_float((unsigned)h << 16);
        hi[i] = (short)h;
        lo[i] = (short)f2bf(f[i] - hf);   // f - hf is exact in f32 (Sterbenz)
    }
}

// ---------------------------------------------------------------------------
// K0: zero the per-node counters (ws is poisoned before every launch).
// ---------------------------------------------------------------------------
__global__ __launch_bounds__(256) void k_zero(int* __restrict__ ncnt) {
    int i = blockIdx.x * 256 + threadIdx.x;
    if (i < NN2) ncnt[i] = 0;
}

// ---------------------------------------------------------------------------
// K1 (fused): blocks [0,NCVT) convert feat f32->bf16; [NCVT,NCVT+NCNTB)
// per-node histogram via global atomics (L2-resident counters); last block
// builds combined W16 hi plane [j][k] (k<64=W_self, k>=64=W_neigh) AND lo
// plane at +D*128.  No LDS anywhere -> full occupancy for the cvt blocks.
// ---------------------------------------------------------------------------
__global__ __launch_bounds__(256) void k_pre(const float4* __restrict__ feat4,
                                             unsigned short* __restrict__ feat16,
                                             const float* __restrict__ Wn,
                                             const float* __restrict__ Ws,
                                             unsigned short* __restrict__ W16,
                                             const int* __restrict__ dst,
                                             int* __restrict__ ncnt) {
    const int b   = blockIdx.x;
    const int tid = threadIdx.x;
    if (b < NCVT) {
        const int i = b * 256 + tid;
        float4 v = feat4[i];
        ushort4 o;
        o.x = f2bf(v.x); o.y = f2bf(v.y); o.z = f2bf(v.z); o.w = f2bf(v.w);
        *(ushort4*)&feat16[(size_t)i * 4] = o;
    } else if (b < NCVT + NCNTB) {
        const int base = (b - NCVT) * EPB2;
        for (int k = tid; k < EPB2; k += 256)
            atomicAdd(&ncnt[dst[base + k]], 1);
    } else {
        for (int e = tid; e < D * 128; e += 256) {
            const int j = e >> 7, k = e & 127;
            const float w = (k < D) ? Ws[j * D + k] : Wn[j * D + (k - D)];
            const unsigned short h = f2bf(w);
            const float hf = __uint_as_float((unsigned)h << 16);
            W16[e] = h;
            W16[D * 128 + e] = f2bf(w - hf);
        }
    }
}

// ---------------------------------------------------------------------------
// K2: exclusive scan of NN2 per-node counts (one 1024-thread block, 98 each:
// serial local sum -> Hillis-Steele block scan -> serial write-back).
// Writes nstart[0..NN2] (sentinel = N_EDGES) and the cursor copy ncur.
// ---------------------------------------------------------------------------
constexpr int SCAN_PER = (NN2 + 1 + 1023) / 1024;   // 98
__global__ __launch_bounds__(1024) void k_nscan(const int* __restrict__ ncnt,
                                                int* __restrict__ nstart,
                                                int* __restrict__ ncur) {
    __shared__ int s[1024];
    const int t    = threadIdx.x;
    const int base = t * SCAN_PER;
    int sum = 0;
    for (int j = 0; j < SCAN_PER; ++j) {
        const int idx = base + j;
        sum += (idx < NN2) ? ncnt[idx] : 0;
    }
    s[t] = sum;
    __syncthreads();
    for (int off = 1; off < 1024; off <<= 1) {
        int u = (t >= off) ? s[t - off] : 0;
        __syncthreads();
        s[t] += u;
        __syncthreads();
    }
    int run = s[t] - sum;     // exclusive prefix of this thread's range
    for (int j = 0; j < SCAN_PER; ++j) {
        const int idx = base + j;
        if (idx <= NN2) {
            nstart[idx] = run;
            if (idx < NN2) { ncur[idx] = run; run += ncnt[idx]; }
        }
    }
}

// ---------------------------------------------------------------------------
// K3: single-pass placement — node-level counting sort. Returning atomics on
// L2-resident cursors pipeline across edges; scattered 8B writes land in the
// 12.8MB entries2 region (1.6MB/XCD L2 slice -> write-back absorbed).
// ---------------------------------------------------------------------------
__global__ __launch_bounds__(256) void k_place(const int* __restrict__ src,
                                               const int* __restrict__ dst,
                                               const float* __restrict__ ew,
                                               int* __restrict__ ncur,
                                               uint2* __restrict__ entries2) {
    const int stride = gridDim.x * 256;
    for (int e = blockIdx.x * 256 + threadIdx.x; e < N_EDGES; e += stride) {
        const int d   = dst[e];
        const int pos = atomicAdd(&ncur[d], 1);
        entries2[pos] = make_uint2((unsigned)src[e], __float_as_uint(ew[e]));
    }
}

// ---------------------------------------------------------------------------
// K4 (aggregate + MFMA finalize). Edge loop unrolled x2: paired entry +
// feat16 gather loads give 2 outstanding gathers per lane (latency-bound fix).
// Numerics identical to the passing R2 version (f32 aggrow, split MFMA).
// ---------------------------------------------------------------------------
__global__ __launch_bounds__(256, 8) void k_bucket(
    const uint2* __restrict__ feat16u2,
    const float* __restrict__ feat32,
    const int* __restrict__ nstart,
    const uint2* __restrict__ entries2,
    const unsigned short* __restrict__ W16,
    const float* __restrict__ bias,
    float* __restrict__ out) {
    __shared__ __align__(16) float aggrow[BN * 68];   // 17.4 KB f32
    __shared__ int hh[BN], st[BN];
    const int tid = threadIdx.x;
    const int b   = blockIdx.x;

    if (tid < BN) {
        const int s = nstart[b * BN + tid];
        const int e = nstart[b * BN + tid + 1];
        st[tid] = s;
        hh[tid] = e - s;
    }
    __syncthreads();

    // P4: aggregate — single acc, 4 lane-groups, stride 4, unroll x2.
    const int wave = tid >> 6, lane = tid & 63;
    const int group = lane >> 4, gl = lane & 15;
    for (int t = 0; t < 16; ++t) {
        const int dl  = wave * 16 + t;
        const int ss  = st[dl];
        const int deg = hh[dl];
        const int se  = ss + deg;
        float4 acc = make_float4(0.f, 0.f, 0.f, 0.f);
        int e = ss + group;
        for (; e + 4 < se; e += 8) {
            const uint2 en0 = entries2[e];
            const uint2 en1 = entries2[e + 4];
            const uint2 p0  = feat16u2[(size_t)en0.x * 16 + gl];
            const uint2 p1  = feat16u2[(size_t)en1.x * 16 + gl];
            const float w0  = __uint_as_float(en0.y);
            const float w1  = __uint_as_float(en1.y);
            acc.x = fmaf(__uint_as_float(p0.x << 16),         w0, acc.x);
            acc.y = fmaf(__uint_as_float(p0.x & 0xFFFF0000u), w0, acc.y);
            acc.z = fmaf(__uint_as_float(p0.y << 16),         w0, acc.z);
            acc.w = fmaf(__uint_as_float(p0.y & 0xFFFF0000u), w0, acc.w);
            acc.x = fmaf(__uint_as_float(p1.x << 16),         w1, acc.x);
            acc.y = fmaf(__uint_as_float(p1.x & 0xFFFF0000u), w1, acc.y);
            acc.z = fmaf(__uint_as_float(p1.y << 16),         w1, acc.z);
            acc.w = fmaf(__uint_as_float(p1.y & 0xFFFF0000u), w1, acc.w);
        }
        if (e < se) {
            const uint2 en = entries2[e];
            const float w  = __uint_as_float(en.y);
            const uint2 p  = feat16u2[(size_t)en.x * 16 + gl];
            acc.x = fmaf(__uint_as_float(p.x << 16),         w, acc.x);
            acc.y = fmaf(__uint_as_float(p.x & 0xFFFF0000u), w, acc.y);
            acc.z = fmaf(__uint_as_float(p.y << 16),         w, acc.z);
            acc.w = fmaf(__uint_as_float(p.y & 0xFFFF0000u), w, acc.w);
        }
#pragma unroll
        for (int m = 16; m <= 32; m <<= 1) {
            acc.x += __shfl_xor(acc.x, m);
            acc.y += __shfl_xor(acc.y, m);
            acc.z += __shfl_xor(acc.z, m);
            acc.w += __shfl_xor(acc.w, m);
        }
        if (group == 0) {
            const float inv = 1.0f / fmaxf((float)deg, 1.0f);
            float4 o = make_float4(acc.x * inv, acc.y * inv, acc.z * inv, acc.w * inv);
            *(float4*)&aggrow[dl * 68 + gl * 4] = o;
        }
    }
    __syncthreads();

    // P5: MFMA finalize with hi/lo split operands (near-f32 numerics).
    const int quad = lane >> 4, r = lane & 15;
    const int node0 = b * BN + wave * 16;
    int arow = node0 + r;
    if (arow > N_NODES - 1) arow = N_NODES - 1;

    bf16x8 ahi[4], alo[4];
    {
        const float* fp = &feat32[(size_t)arow * 64 + quad * 8];
        split8(*(const float4*)fp,        *(const float4*)(fp + 4),  ahi[0], alo[0]);
        split8(*(const float4*)(fp + 32), *(const float4*)(fp + 36), ahi[1], alo[1]);
        const float* ap = &aggrow[(wave * 16 + r) * 68 + quad * 8];
        split8(*(const float4*)ap,        *(const float4*)(ap + 4),  ahi[2], alo[2]);
        split8(*(const float4*)(ap + 32), *(const float4*)(ap + 36), ahi[3], alo[3]);
    }

    const unsigned short* W16lo = W16 + D * 128;
    f32x4 acc4[4] = {};
#pragma unroll
    for (int nt = 0; nt < 4; ++nt) {
#pragma unroll
        for (int kc = 0; kc < 4; ++kc) {
            const size_t wo = (size_t)(nt * 16 + r) * 128 + kc * 32 + quad * 8;
            const bf16x8 bhi = *(const bf16x8*)&W16[wo];
            const bf16x8 blo = *(const bf16x8*)&W16lo[wo];
            acc4[nt] = __builtin_amdgcn_mfma_f32_16x16x32_bf16(ahi[kc], bhi, acc4[nt], 0, 0, 0);
            acc4[nt] = __builtin_amdgcn_mfma_f32_16x16x32_bf16(alo[kc], bhi, acc4[nt], 0, 0, 0);
            acc4[nt] = __builtin_amdgcn_mfma_f32_16x16x32_bf16(ahi[kc], blo, acc4[nt], 0, 0, 0);
        }
    }

#pragma unroll
    for (int nt = 0; nt < 4; ++nt) {
        const float bv = bias[nt * 16 + r];
#pragma unroll
        for (int reg = 0; reg < 4; ++reg) {
            const int m = node0 + quad * 4 + reg;
            if (m < N_NODES) out[(size_t)m * 64 + nt * 16 + r] = acc4[nt][reg] + bv;
        }
    }
}

// ---------------------------------------------------------------------------
// Fallback path (R1): atomic scatter + shuffle finalize, if ws is too small.
// ---------------------------------------------------------------------------
__global__ __launch_bounds__(256) void fb_zero(float4* __restrict__ out4,
                                               float* __restrict__ deg) {
    const int stride = gridDim.x * blockDim.x;
    int i = blockIdx.x * blockDim.x + threadIdx.x;
    const int total4 = (N_NODES * D) / 4;
    for (int idx = i; idx < total4; idx += stride)
        out4[idx] = make_float4(0.f, 0.f, 0.f, 0.f);
    for (int idx = i; idx < N_NODES; idx += stride)
        deg[idx] = 0.f;
}

__global__ __launch_bounds__(256) void fb_scatter(
    const float* __restrict__ feat, const int* __restrict__ src,
    const int* __restrict__ dst, const float* __restrict__ ew,
    float* __restrict__ out, float* __restrict__ deg) {
    const int gid  = blockIdx.x * blockDim.x + threadIdx.x;
    const int e    = gid >> 6;
    const int lane = gid & 63;
    if (e >= N_EDGES) return;
    atomicAdd(&out[(size_t)dst[e] * D + lane], feat[(size_t)src[e] * D + lane] * ew[e]);
    if (lane == 0) atomicAdd(&deg[dst[e]], 1.0f);
}

__global__ __launch_bounds__(256) void fb_finalize(
    const float* __restrict__ feat, const float* __restrict__ Wn,
    const float* __restrict__ Ws, const float* __restrict__ bias,
    const float* __restrict__ deg, float* __restrict__ out) {
    __shared__ float lWn[D * 65];
    __shared__ float lWs[D * 65];
    for (int idx = threadIdx.x; idx < D * D; idx += 256) {
        const int r = idx >> 6, c = idx & 63;
        lWn[r * 65 + c] = Wn[idx];
        lWs[r * 65 + c] = Ws[idx];
    }
    __syncthreads();
    const int wave = threadIdx.x >> 6;
    const int lane = threadIdx.x & 63;
    const int n = blockIdx.x * 4 + wave;
    if (n >= N_NODES) return;
    const float f  = feat[(size_t)n * D + lane];
    const float sv = out[(size_t)n * D + lane];
    const float inv = 1.0f / fmaxf(deg[n], 1.0f);
    float acc_s = 0.f, acc_n = 0.f;
#pragma unroll
    for (int k = 0; k < D; ++k) {
        acc_s += __shfl(f, k)  * lWs[lane * 65 + k];
        acc_n += __shfl(sv, k) * lWn[lane * 65 + k];
    }
    out[(size_t)n * D + lane] = acc_s + acc_n * inv + bias[lane];
}

// ---------------------------------------------------------------------------
extern "C" void kernel_launch(void* const* d_in, const int* in_sizes, int n_in,
                              void* d_out, int out_size, void* d_ws, size_t ws_size,
                              hipStream_t stream) {
    const float* feat = (const float*)d_in[0];
    const int*   src  = (const int*)  d_in[1];
    const int*   dst  = (const int*)  d_in[2];
    const float* ew   = (const float*)d_in[3];
    const float* Wn   = (const float*)d_in[4];
    const float* Ws   = (const float*)d_in[5];
    const float* bias = (const float*)d_in[6];
    float* out = (float*)d_out;
    char* ws = (char*)d_ws;

    if (ws_size >= WS_NEEDED) {
        int* ncnt   = (int*)(ws + OFF_NCNT);
        int* nstart = (int*)(ws + OFF_NSTART);
        int* ncur   = (int*)(ws + OFF_NCUR);
        unsigned short* W16    = (unsigned short*)(ws + OFF_W16);
        unsigned short* feat16 = (unsigned short*)(ws + OFF_FEAT16);
        uint2* entries2 = (uint2*)(ws + OFF_ENT2);

        k_zero  <<<(NN2 + 255) / 256, 256, 0, stream>>>(ncnt);
        k_pre   <<<NCVT + NCNTB + 1, 256, 0, stream>>>((const float4*)feat, feat16,
                                                       Wn, Ws, W16, dst, ncnt);
        k_nscan <<<1, 1024, 0, stream>>>(ncnt, nstart, ncur);
        k_place <<<NPLACE, 256, 0, stream>>>(src, dst, ew, ncur, entries2);
        k_bucket<<<NBUCK, 256, 0, stream>>>((const uint2*)feat16, feat, nstart,
                                            entries2, W16, bias, out);
    } else {
        float* deg = (float*)d_ws;
        fb_zero<<<2048, 256, 0, stream>>>((float4*)out, deg);
        fb_scatter<<<(N_EDGES * 64) / 256, 256, 0, stream>>>(feat, src, dst, ew, out, deg);
        fb_finalize<<<(N_NODES + 3) / 4, 256, 0, stream>>>(feat, Wn, Ws, bias, deg, out);
    }
}

// Round 5
// 357.813 us; speedup vs baseline: 1.7046x; 1.7046x over previous
//
#include <hip/hip_runtime.h>

// Problem constants (from reference)
constexpr int N_NODES = 100000;
constexpr int N_EDGES = 1600000;
constexpr int D = 64;          // D_IN == D_OUT == 64

// Bucketing: 64 consecutive dst nodes per bucket (one k_bucket block each).
constexpr int BSH    = 6;
constexpr int BN     = 1 << BSH;                              // 64
constexpr int NBUCK  = (N_NODES + BN - 1) / BN;               // 1563
constexpr int NN2    = NBUCK * BN;                            // 100032 (padded nodes)
constexpr int NCNTB  = 800;                                   // count blocks
constexpr int EPB2   = N_EDGES / NCNTB;                       // 2000 (exact)
constexpr int NCVT   = (N_NODES * D / 4) / 256;               // 6250 cvt blocks
constexpr int NPLACE = 1024;                                  // placement blocks
constexpr int NSB    = (NN2 + 1 + 1023) / 1024;               // 98 scan blocks

// ---------------------------------------------------------------------------
// Workspace layout (bytes). Total 27,234,816 <= 40,280,064 (verified avail).
// Single-level per-node counting sort with hierarchical 3-phase scan.
// ---------------------------------------------------------------------------
constexpr size_t OFF_NCNT    = 0;                              // NN2 ints
constexpr size_t OFF_NSTART  = 400384;                         // NN2+1 ints
constexpr size_t OFF_NCUR    = 800768;                         // NN2 ints
constexpr size_t OFF_TMP     = 1201152;                        // NN2+1 ints (local scans)
constexpr size_t OFF_BSUM    = 1601536;                        // NSB ints
constexpr size_t OFF_W16     = 1602048;                        // 32 KB (hi+lo planes)
constexpr size_t OFF_FEAT16  = 1634816;                        // N_NODES*64 bf16
constexpr size_t OFF_ENT2    = OFF_FEAT16 + (size_t)N_NODES * D * 2;   // 14,434,816
constexpr size_t WS_NEEDED   = OFF_ENT2 + (size_t)N_EDGES * 8;         // 27,234,816

typedef short  bf16x8 __attribute__((ext_vector_type(8)));
typedef float  f32x4  __attribute__((ext_vector_type(4)));

__device__ __forceinline__ unsigned short f2bf(float f) {   // RNE f32 -> bf16
    unsigned u = __float_as_uint(f);
    u += 0x7fffu + ((u >> 16) & 1u);
    return (unsigned short)(u >> 16);
}

// Split 8 consecutive f32 into hi/lo bf16 fragments (hi = RNE(f), lo = RNE(f - hi)).
// Residual after the split is ~2^-16 relative: near-f32 via 3-product MFMA.
__device__ __forceinline__ void split8(float4 p0, float4 p1, bf16x8& hi, bf16x8& lo) {
    float f[8] = {p0.x, p0.y, p0.z, p0.w, p1.x, p1.y, p1.z, p1.w};
#pragma unroll
    for (int i = 0; i < 8; ++i) {
        const unsigned short h = f2bf(f[i]);
        const float hf = __uint_as_float((unsigned)h << 16);
        hi[i] = (short)h;
        lo[i] = (short)f2bf(f[i] - hf);   // f - hf is exact in f32 (Sterbenz)
    }
}

// ---------------------------------------------------------------------------
// K0: zero the per-node counters (ws is poisoned before every launch).
// ---------------------------------------------------------------------------
__global__ __launch_bounds__(256) void k_zero(int* __restrict__ ncnt) {
    int i = blockIdx.x * 256 + threadIdx.x;
    if (i < NN2) ncnt[i] = 0;
}

// ---------------------------------------------------------------------------
// K1 (fused): blocks [0,NCVT) convert feat f32->bf16; [NCVT,NCVT+NCNTB)
// per-node histogram via global atomics (L2-resident counters); last block
// builds combined W16 hi plane [j][k] (k<64=W_self, k>=64=W_neigh) AND lo
// plane at +D*128.
// ---------------------------------------------------------------------------
__global__ __launch_bounds__(256) void k_pre(const float4* __restrict__ feat4,
                                             unsigned short* __restrict__ feat16,
                                             const float* __restrict__ Wn,
                                             const float* __restrict__ Ws,
                                             unsigned short* __restrict__ W16,
                                             const int* __restrict__ dst,
                                             int* __restrict__ ncnt) {
    const int b   = blockIdx.x;
    const int tid = threadIdx.x;
    if (b < NCVT) {
        const int i = b * 256 + tid;
        float4 v = feat4[i];
        ushort4 o;
        o.x = f2bf(v.x); o.y = f2bf(v.y); o.z = f2bf(v.z); o.w = f2bf(v.w);
        *(ushort4*)&feat16[(size_t)i * 4] = o;
    } else if (b < NCVT + NCNTB) {
        const int base = (b - NCVT) * EPB2;
        for (int k = tid; k < EPB2; k += 256)
            atomicAdd(&ncnt[dst[base + k]], 1);
    } else {
        for (int e = tid; e < D * 128; e += 256) {
            const int j = e >> 7, k = e & 127;
            const float w = (k < D) ? Ws[j * D + k] : Wn[j * D + (k - D)];
            const unsigned short h = f2bf(w);
            const float hf = __uint_as_float((unsigned)h << 16);
            W16[e] = h;
            W16[D * 128 + e] = f2bf(w - hf);
        }
    }
}

// ---------------------------------------------------------------------------
// K2a/b/c: hierarchical exclusive scan of NN2+1 per-node counts.
// (R3's single-block serial scan was 257 us: 1 CU, strided reads. This is
// coalesced and spread over all CUs.)
// ---------------------------------------------------------------------------
__global__ __launch_bounds__(1024) void k_scan_a(const int* __restrict__ ncnt,
                                                 int* __restrict__ tmp,
                                                 int* __restrict__ bsum) {
    __shared__ int s[1024];
    const int t   = threadIdx.x;
    const int gid = blockIdx.x * 1024 + t;
    const int v   = (gid < NN2) ? ncnt[gid] : 0;
    s[t] = v;
    __syncthreads();
    for (int off = 1; off < 1024; off <<= 1) {
        int u = (t >= off) ? s[t - off] : 0;
        __syncthreads();
        s[t] += u;
        __syncthreads();
    }
    if (gid <= NN2) tmp[gid] = s[t] - v;     // block-local exclusive
    if (t == 1023) bsum[blockIdx.x] = s[t];  // block total
}

__global__ __launch_bounds__(128) void k_scan_b(int* __restrict__ bsum) {
    __shared__ int s[128];
    const int t = threadIdx.x;
    const int v = (t < NSB) ? bsum[t] : 0;
    s[t] = v;
    __syncthreads();
    for (int off = 1; off < 128; off <<= 1) {
        int u = (t >= off) ? s[t - off] : 0;
        __syncthreads();
        s[t] += u;
        __syncthreads();
    }
    if (t < NSB) bsum[t] = s[t] - v;         // exclusive block offsets
}

__global__ __launch_bounds__(1024) void k_scan_c(const int* __restrict__ tmp,
                                                 const int* __restrict__ bsum,
                                                 int* __restrict__ nstart,
                                                 int* __restrict__ ncur) {
    const int gid = blockIdx.x * 1024 + threadIdx.x;
    if (gid <= NN2) {
        const int val = tmp[gid] + bsum[blockIdx.x];
        nstart[gid] = val;
        if (gid < NN2) ncur[gid] = val;
    }
}

// ---------------------------------------------------------------------------
// K3: single-pass placement — node-level counting sort. Returning atomics on
// L2-resident cursors pipeline across edges; scattered 8B writes land in the
// 12.8MB entries2 region.
// ---------------------------------------------------------------------------
__global__ __launch_bounds__(256) void k_place(const int* __restrict__ src,
                                               const int* __restrict__ dst,
                                               const float* __restrict__ ew,
                                               int* __restrict__ ncur,
                                               uint2* __restrict__ entries2) {
    const int stride = gridDim.x * 256;
    for (int e = blockIdx.x * 256 + threadIdx.x; e < N_EDGES; e += stride) {
        const int d   = dst[e];
        const int pos = atomicAdd(&ncur[d], 1);
        entries2[pos] = make_uint2((unsigned)src[e], __float_as_uint(ew[e]));
    }
}

// ---------------------------------------------------------------------------
// K4 (aggregate + MFMA finalize). Edge loop unrolled x2: paired entry +
// feat16 gather loads give 2 outstanding gathers per lane.
// Numerics identical to the passing R2/R3 versions (f32 aggrow, split MFMA).
// ---------------------------------------------------------------------------
__global__ __launch_bounds__(256, 8) void k_bucket(
    const uint2* __restrict__ feat16u2,
    const float* __restrict__ feat32,
    const int* __restrict__ nstart,
    const uint2* __restrict__ entries2,
    const unsigned short* __restrict__ W16,
    const float* __restrict__ bias,
    float* __restrict__ out) {
    __shared__ __align__(16) float aggrow[BN * 68];   // 17.4 KB f32
    __shared__ int hh[BN], st[BN];
    const int tid = threadIdx.x;
    const int b   = blockIdx.x;

    if (tid < BN) {
        const int s = nstart[b * BN + tid];
        const int e = nstart[b * BN + tid + 1];
        st[tid] = s;
        hh[tid] = e - s;
    }
    __syncthreads();

    // P4: aggregate — single acc, 4 lane-groups, stride 4, unroll x2.
    const int wave = tid >> 6, lane = tid & 63;
    const int group = lane >> 4, gl = lane & 15;
    for (int t = 0; t < 16; ++t) {
        const int dl  = wave * 16 + t;
        const int ss  = st[dl];
        const int deg = hh[dl];
        const int se  = ss + deg;
        float4 acc = make_float4(0.f, 0.f, 0.f, 0.f);
        int e = ss + group;
        for (; e + 4 < se; e += 8) {
            const uint2 en0 = entries2[e];
            const uint2 en1 = entries2[e + 4];
            const uint2 p0  = feat16u2[(size_t)en0.x * 16 + gl];
            const uint2 p1  = feat16u2[(size_t)en1.x * 16 + gl];
            const float w0  = __uint_as_float(en0.y);
            const float w1  = __uint_as_float(en1.y);
            acc.x = fmaf(__uint_as_float(p0.x << 16),         w0, acc.x);
            acc.y = fmaf(__uint_as_float(p0.x & 0xFFFF0000u), w0, acc.y);
            acc.z = fmaf(__uint_as_float(p0.y << 16),         w0, acc.z);
            acc.w = fmaf(__uint_as_float(p0.y & 0xFFFF0000u), w0, acc.w);
            acc.x = fmaf(__uint_as_float(p1.x << 16),         w1, acc.x);
            acc.y = fmaf(__uint_as_float(p1.x & 0xFFFF0000u), w1, acc.y);
            acc.z = fmaf(__uint_as_float(p1.y << 16),         w1, acc.z);
            acc.w = fmaf(__uint_as_float(p1.y & 0xFFFF0000u), w1, acc.w);
        }
        if (e < se) {
            const uint2 en = entries2[e];
            const float w  = __uint_as_float(en.y);
            const uint2 p  = feat16u2[(size_t)en.x * 16 + gl];
            acc.x = fmaf(__uint_as_float(p.x << 16),         w, acc.x);
            acc.y = fmaf(__uint_as_float(p.x & 0xFFFF0000u), w, acc.y);
            acc.z = fmaf(__uint_as_float(p.y << 16),         w, acc.z);
            acc.w = fmaf(__uint_as_float(p.y & 0xFFFF0000u), w, acc.w);
        }
#pragma unroll
        for (int m = 16; m <= 32; m <<= 1) {
            acc.x += __shfl_xor(acc.x, m);
            acc.y += __shfl_xor(acc.y, m);
            acc.z += __shfl_xor(acc.z, m);
            acc.w += __shfl_xor(acc.w, m);
        }
        if (group == 0) {
            const float inv = 1.0f / fmaxf((float)deg, 1.0f);
            float4 o = make_float4(acc.x * inv, acc.y * inv, acc.z * inv, acc.w * inv);
            *(float4*)&aggrow[dl * 68 + gl * 4] = o;
        }
    }
    __syncthreads();

    // P5: MFMA finalize with hi/lo split operands (near-f32 numerics).
    const int quad = lane >> 4, r = lane & 15;
    const int node0 = b * BN + wave * 16;
    int arow = node0 + r;
    if (arow > N_NODES - 1) arow = N_NODES - 1;

    bf16x8 ahi[4], alo[4];
    {
        const float* fp = &feat32[(size_t)arow * 64 + quad * 8];
        split8(*(const float4*)fp,        *(const float4*)(fp + 4),  ahi[0], alo[0]);
        split8(*(const float4*)(fp + 32), *(const float4*)(fp + 36), ahi[1], alo[1]);
        const float* ap = &aggrow[(wave * 16 + r) * 68 + quad * 8];
        split8(*(const float4*)ap,        *(const float4*)(ap + 4),  ahi[2], alo[2]);
        split8(*(const float4*)(ap + 32), *(const float4*)(ap + 36), ahi[3], alo[3]);
    }

    const unsigned short* W16lo = W16 + D * 128;
    f32x4 acc4[4] = {};
#pragma unroll
    for (int nt = 0; nt < 4; ++nt) {
#pragma unroll
        for (int kc = 0; kc < 4; ++kc) {
            const size_t wo = (size_t)(nt * 16 + r) * 128 + kc * 32 + quad * 8;
            const bf16x8 bhi = *(const bf16x8*)&W16[wo];
            const bf16x8 blo = *(const bf16x8*)&W16lo[wo];
            acc4[nt] = __builtin_amdgcn_mfma_f32_16x16x32_bf16(ahi[kc], bhi, acc4[nt], 0, 0, 0);
            acc4[nt] = __builtin_amdgcn_mfma_f32_16x16x32_bf16(alo[kc], bhi, acc4[nt], 0, 0, 0);
            acc4[nt] = __builtin_amdgcn_mfma_f32_16x16x32_bf16(ahi[kc], blo, acc4[nt], 0, 0, 0);
        }
    }

#pragma unroll
    for (int nt = 0; nt < 4; ++nt) {
        const float bv = bias[nt * 16 + r];
#pragma unroll
        for (int reg = 0; reg < 4; ++reg) {
            const int m = node0 + quad * 4 + reg;
            if (m < N_NODES) out[(size_t)m * 64 + nt * 16 + r] = acc4[nt][reg] + bv;
        }
    }
}

// ---------------------------------------------------------------------------
// Fallback path (R1): atomic scatter + shuffle finalize, if ws is too small.
// ---------------------------------------------------------------------------
__global__ __launch_bounds__(256) void fb_zero(float4* __restrict__ out4,
                                               float* __restrict__ deg) {
    const int stride = gridDim.x * blockDim.x;
    int i = blockIdx.x * blockDim.x + threadIdx.x;
    const int total4 = (N_NODES * D) / 4;
    for (int idx = i; idx < total4; idx += stride)
        out4[idx] = make_float4(0.f, 0.f, 0.f, 0.f);
    for (int idx = i; idx < N_NODES; idx += stride)
        deg[idx] = 0.f;
}

__global__ __launch_bounds__(256) void fb_scatter(
    const float* __restrict__ feat, const int* __restrict__ src,
    const int* __restrict__ dst, const float* __restrict__ ew,
    float* __restrict__ out, float* __restrict__ deg) {
    const int gid  = blockIdx.x * blockDim.x + threadIdx.x;
    const int e    = gid >> 6;
    const int lane = gid & 63;
    if (e >= N_EDGES) return;
    atomicAdd(&out[(size_t)dst[e] * D + lane], feat[(size_t)src[e] * D + lane] * ew[e]);
    if (lane == 0) atomicAdd(&deg[dst[e]], 1.0f);
}

__global__ __launch_bounds__(256) void fb_finalize(
    const float* __restrict__ feat, const float* __restrict__ Wn,
    const float* __restrict__ Ws, const float* __restrict__ bias,
    const float* __restrict__ deg, float* __restrict__ out) {
    __shared__ float lWn[D * 65];
    __shared__ float lWs[D * 65];
    for (int idx = threadIdx.x; idx < D * D; idx += 256) {
        const int r = idx >> 6, c = idx & 63;
        lWn[r * 65 + c] = Wn[idx];
        lWs[r * 65 + c] = Ws[idx];
    }
    __syncthreads();
    const int wave = threadIdx.x >> 6;
    const int lane = threadIdx.x & 63;
    const int n = blockIdx.x * 4 + wave;
    if (n >= N_NODES) return;
    const float f  = feat[(size_t)n * D + lane];
    const float sv = out[(size_t)n * D + lane];
    const float inv = 1.0f / fmaxf(deg[n], 1.0f);
    float acc_s = 0.f, acc_n = 0.f;
#pragma unroll
    for (int k = 0; k < D; ++k) {
        acc_s += __shfl(f, k)  * lWs[lane * 65 + k];
        acc_n += __shfl(sv, k) * lWn[lane * 65 + k];
    }
    out[(size_t)n * D + lane] = acc_s + acc_n * inv + bias[lane];
}

// ---------------------------------------------------------------------------
extern "C" void kernel_launch(void* const* d_in, const int* in_sizes, int n_in,
                              void* d_out, int out_size, void* d_ws, size_t ws_size,
                              hipStream_t stream) {
    const float* feat = (const float*)d_in[0];
    const int*   src  = (const int*)  d_in[1];
    const int*   dst  = (const int*)  d_in[2];
    const float* ew   = (const float*)d_in[3];
    const float* Wn   = (const float*)d_in[4];
    const float* Ws   = (const float*)d_in[5];
    const float* bias = (const float*)d_in[6];
    float* out = (float*)d_out;
    char* ws = (char*)d_ws;

    if (ws_size >= WS_NEEDED) {
        int* ncnt   = (int*)(ws + OFF_NCNT);
        int* nstart = (int*)(ws + OFF_NSTART);
        int* ncur   = (int*)(ws + OFF_NCUR);
        int* tmp    = (int*)(ws + OFF_TMP);
        int* bsum   = (int*)(ws + OFF_BSUM);
        unsigned short* W16    = (unsigned short*)(ws + OFF_W16);
        unsigned short* feat16 = (unsigned short*)(ws + OFF_FEAT16);
        uint2* entries2 = (uint2*)(ws + OFF_ENT2);

        k_zero  <<<(NN2 + 255) / 256, 256, 0, stream>>>(ncnt);
        k_pre   <<<NCVT + NCNTB + 1, 256, 0, stream>>>((const float4*)feat, feat16,
                                                       Wn, Ws, W16, dst, ncnt);
        k_scan_a<<<NSB, 1024, 0, stream>>>(ncnt, tmp, bsum);
        k_scan_b<<<1, 128, 0, stream>>>(bsum);
        k_scan_c<<<NSB, 1024, 0, stream>>>(tmp, bsum, nstart, ncur);
        k_place <<<NPLACE, 256, 0, stream>>>(src, dst, ew, ncur, entries2);
        k_bucket<<<NBUCK, 256, 0, stream>>>((const uint2*)feat16, feat, nstart,
                                            entries2, W16, bias, out);
    } else {
        float* deg = (float*)d_ws;
        fb_zero<<<2048, 256, 0, stream>>>((float4*)out, deg);
        fb_scatter<<<(N_EDGES * 64) / 256, 256, 0, stream>>>(feat, src, dst, ew, out, deg);
        fb_finalize<<<(N_NODES + 3) / 4, 256, 0, stream>>>(feat, Wn, Ws, bias, deg, out);
    }
}

// Round 7
// 307.310 us; speedup vs baseline: 1.9847x; 1.1643x over previous
//
#include <hip/hip_runtime.h>

// Problem constants (from reference)
constexpr int N_NODES = 100000;
constexpr int N_EDGES = 1600000;
constexpr int D = 64;          // D_IN == D_OUT == 64

// Bucketing: 64 consecutive dst nodes per bucket (one k_bucket block each).
constexpr int BSH    = 6;
constexpr int BN     = 1 << BSH;                              // 64
constexpr int NBUCK  = (N_NODES + BN - 1) / BN;               // 1563
constexpr int NN2    = NBUCK * BN;                            // 100032 (padded nodes)
constexpr int NCNTB  = 800;                                   // bin-hist blocks
constexpr int EPB2   = N_EDGES / NCNTB;                       // 2000 (exact)
constexpr int NCVT   = (N_NODES * D / 4) / 256;               // 6250 cvt blocks
constexpr int NSB    = (NN2 + 1 + 1023) / 1024;               // 98 scan blocks
constexpr int NBINS  = (NN2 + 1023) >> 10;                    // 98 coarse bins (1024 nodes)
constexpr int CHUNK  = 8192;                                  // pass-A edges per block
constexpr int NPA    = (N_EDGES + CHUNK - 1) / CHUNK;         // 196 pass-A blocks

// ---------------------------------------------------------------------------
// Workspace layout (bytes). Total 40,034,816 <= 40,280,064 (verified avail).
// Two-pass binned counting sort (fixes 8x write amplification of R5 k_place).
// ---------------------------------------------------------------------------
constexpr size_t OFF_NCNT     = 0;                             // NN2 ints
constexpr size_t OFF_NSTART   = 400384;                        // NN2+1 ints
constexpr size_t OFF_BINCNT   = 800768;                        // NBINS ints
constexpr size_t OFF_BINSTART = 801280;                        // NBINS+1 ints
constexpr size_t OFF_BINCUR   = 801792;                        // NBINS ints
constexpr size_t OFF_TMP      = 1201152;                       // NN2+1 ints (local scans)
constexpr size_t OFF_BSUM     = 1601536;                       // NSB ints
constexpr size_t OFF_W16      = 1602048;                       // 32 KB (hi+lo planes)
constexpr size_t OFF_FEAT16   = 1634816;                       // N_NODES*64 bf16
constexpr size_t OFF_ENT2     = OFF_FEAT16 + (size_t)N_NODES * D * 2;  // 14,434,816
constexpr size_t OFF_ENTA     = OFF_ENT2 + (size_t)N_EDGES * 8;        // 27,234,816
constexpr size_t WS_NEEDED    = OFF_ENTA + (size_t)N_EDGES * 8;        // 40,034,816

typedef short  bf16x8 __attribute__((ext_vector_type(8)));
typedef float  f32x4  __attribute__((ext_vector_type(4)));

__device__ __forceinline__ unsigned short f2bf(float f) {   // RNE f32 -> bf16
    unsigned u = __float_as_uint(f);
    u += 0x7fffu + ((u >> 16) & 1u);
    return (unsigned short)(u >> 16);
}

// Split 8 consecutive f32 into hi/lo bf16 fragments (hi = RNE(f), lo = RNE(f - hi)).
// Residual after the split is ~2^-16 relative: near-f32 via 3-product MFMA.
__device__ __forceinline__ void split8(float4 p0, float4 p1, bf16x8& hi, bf16x8& lo) {
    float f[8] = {p0.x, p0.y, p0.z, p0.w, p1.x, p1.y, p1.z, p1.w};
#pragma unroll
    for (int i = 0; i < 8; ++i) {
        const unsigned short h = f2bf(f[i]);
        const float hf = __uint_as_float((unsigned)h << 16);
        hi[i] = (short)h;
        lo[i] = (short)f2bf(f[i] - hf);   // f - hf is exact in f32 (Sterbenz)
    }
}

// ---------------------------------------------------------------------------
// K0: zero per-node + per-bin counters (ws is poisoned before every launch).
// ---------------------------------------------------------------------------
__global__ __launch_bounds__(256) void k_zero(int* __restrict__ ncnt,
                                              int* __restrict__ bincnt) {
    int i = blockIdx.x * 256 + threadIdx.x;
    if (i < NN2) ncnt[i] = 0;
    if (i < NBINS) bincnt[i] = 0;
}

// ---------------------------------------------------------------------------
// K1 (fused): blocks [0,NCVT) convert feat f32->bf16; [NCVT,NCVT+NCNTB)
// LDS bin-level histogram (98 counters) -> global bincnt; last block builds
// combined W16 hi plane [j][k] (k<64=W_self, k>=64=W_neigh) AND lo plane.
// ---------------------------------------------------------------------------
__global__ __launch_bounds__(256) void k_pre(const float4* __restrict__ feat4,
                                             unsigned short* __restrict__ feat16,
                                             const float* __restrict__ Wn,
                                             const float* __restrict__ Ws,
                                             unsigned short* __restrict__ W16,
                                             const int* __restrict__ dst,
                                             int* __restrict__ bincnt) {
    __shared__ int l[NBINS];
    const int b   = blockIdx.x;
    const int tid = threadIdx.x;
    if (b < NCVT) {
        const int i = b * 256 + tid;
        float4 v = feat4[i];
        ushort4 o;
        o.x = f2bf(v.x); o.y = f2bf(v.y); o.z = f2bf(v.z); o.w = f2bf(v.w);
        *(ushort4*)&feat16[(size_t)i * 4] = o;
    } else if (b < NCVT + NCNTB) {
        for (int i = tid; i < NBINS; i += 256) l[i] = 0;
        __syncthreads();
        const int base = (b - NCVT) * EPB2;
        for (int k = tid; k < EPB2; k += 256)
            atomicAdd(&l[dst[base + k] >> 10], 1);
        __syncthreads();
        for (int i = tid; i < NBINS; i += 256)
            if (l[i]) atomicAdd(&bincnt[i], l[i]);
    } else {
        for (int e = tid; e < D * 128; e += 256) {
            const int j = e >> 7, k = e & 127;
            const float w = (k < D) ? Ws[j * D + k] : Wn[j * D + (k - D)];
            const unsigned short h = f2bf(w);
            const float hf = __uint_as_float((unsigned)h << 16);
            W16[e] = h;
            W16[D * 128 + e] = f2bf(w - hf);
        }
    }
}

// ---------------------------------------------------------------------------
// K2bin: tiny exclusive scan of 98 bin counts -> binstart (+sentinel), bincur.
// ---------------------------------------------------------------------------
__global__ __launch_bounds__(128) void k_scan_bins(const int* __restrict__ bincnt,
                                                   int* __restrict__ binstart,
                                                   int* __restrict__ bincur) {
    __shared__ int s[128];
    const int t = threadIdx.x;
    const int v = (t < NBINS) ? bincnt[t] : 0;
    s[t] = v;
    __syncthreads();
    for (int off = 1; off < 128; off <<= 1) {
        int u = (t >= off) ? s[t - off] : 0;
        __syncthreads();
        s[t] += u;
        __syncthreads();
    }
    if (t < NBINS) { binstart[t] = s[t] - v; bincur[t] = s[t] - v; }
    if (t == 0) binstart[NBINS] = N_EDGES;
}

// ---------------------------------------------------------------------------
// K3a: pass A — LDS-staged partition of edges into 98 coarse bins (1024 dst
// nodes each). Flush is contiguous runs (avg 84 entries) -> coalesced writes,
// killing R5's 8x scattered-write amplification. Per-node histogram (ncnt
// global atomics) is fused here. entriesA.x = src | (dst&1023)<<17.
// ---------------------------------------------------------------------------
__global__ __launch_bounds__(256) void k_place_a(const int* __restrict__ src,
                                                 const int* __restrict__ dst,
                                                 const float* __restrict__ ew,
                                                 int* __restrict__ ncnt,
                                                 int* __restrict__ bincur,
                                                 uint2* __restrict__ entriesA) {
    __shared__ __align__(16) uint2 stage[CHUNK];       // 64 KB
    __shared__ unsigned char sbin[CHUNK];              // 8 KB
    __shared__ int hist[NBINS], lstart[NBINS], lcur[NBINS], gbase[NBINS];
    __shared__ int s[256];
    const int tid = threadIdx.x;
    const int e0  = blockIdx.x * CHUNK;
    const int cnt = min(CHUNK, N_EDGES - e0);

    for (int i = tid; i < NBINS; i += 256) hist[i] = 0;
    __syncthreads();
    for (int k = tid; k < cnt; k += 256) {
        const int d = dst[e0 + k];
        atomicAdd(&hist[d >> 10], 1);
        atomicAdd(&ncnt[d], 1);        // fused per-node histogram
    }
    __syncthreads();
    // block-local exclusive scan of 98 bin counts (256-wide Hillis-Steele)
    {
        const int v = (tid < NBINS) ? hist[tid] : 0;
        s[tid] = v;
        __syncthreads();
        for (int off = 1; off < 256; off <<= 1) {
            int u = (tid >= off) ? s[tid - off] : 0;
            __syncthreads();
            s[tid] += u;
            __syncthreads();
        }
        if (tid < NBINS) {
            const int ex = s[tid] - v;
            lstart[tid] = ex;
            lcur[tid]   = ex;
            gbase[tid]  = v ? atomicAdd(&bincur[tid], v) : 0;
        }
    }
    __syncthreads();
    // stage entries into LDS grouped by bin
    for (int k = tid; k < cnt; k += 256) {
        const int d = dst[e0 + k];
        const int b = d >> 10;
        const int p = atomicAdd(&lcur[b], 1);
        stage[p] = make_uint2((unsigned)src[e0 + k] | ((unsigned)(d & 1023) << 17),
                              __float_as_uint(ew[e0 + k]));
        sbin[p]  = (unsigned char)b;
    }
    __syncthreads();
    // flush: consecutive slots -> consecutive global addresses per bin run
    for (int j = tid; j < cnt; j += 256) {
        const int b = sbin[j];
        entriesA[gbase[b] + (j - lstart[b])] = stage[j];
    }
}

// ---------------------------------------------------------------------------
// K2a/b/c: hierarchical exclusive scan of NN2+1 per-node counts (R4-verified).
// ---------------------------------------------------------------------------
__global__ __launch_bounds__(1024) void k_scan_a(const int* __restrict__ ncnt,
                                                 int* __restrict__ tmp,
                                                 int* __restrict__ bsum) {
    __shared__ int s[1024];
    const int t   = threadIdx.x;
    const int gid = blockIdx.x * 1024 + t;
    const int v   = (gid < NN2) ? ncnt[gid] : 0;
    s[t] = v;
    __syncthreads();
    for (int off = 1; off < 1024; off <<= 1) {
        int u = (t >= off) ? s[t - off] : 0;
        __syncthreads();
        s[t] += u;
        __syncthreads();
    }
    if (gid <= NN2) tmp[gid] = s[t] - v;     // block-local exclusive
    if (t == 1023) bsum[blockIdx.x] = s[t];  // block total
}

__global__ __launch_bounds__(128) void k_scan_b(int* __restrict__ bsum) {
    __shared__ int s[128];
    const int t = threadIdx.x;
    const int v = (t < NSB) ? bsum[t] : 0;
    s[t] = v;
    __syncthreads();
    for (int off = 1; off < 128; off <<= 1) {
        int u = (t >= off) ? s[t - off] : 0;
        __syncthreads();
        s[t] += u;
        __syncthreads();
    }
    if (t < NSB) bsum[t] = s[t] - v;         // exclusive block offsets
}

__global__ __launch_bounds__(1024) void k_scan_c(const int* __restrict__ tmp,
                                                 const int* __restrict__ bsum,
                                                 int* __restrict__ nstart) {
    const int gid = blockIdx.x * 1024 + threadIdx.x;
    if (gid <= NN2) nstart[gid] = tmp[gid] + bsum[blockIdx.x];
}

// ---------------------------------------------------------------------------
// K3b: pass B — one 1024-thread block per bin (single CU => single XCD).
// Per-node cursors in LDS (absolute positions seeded from nstart); scattered
// writes span only the bin's ~130KB window inside ONE L2 -> lines fully
// accumulate before write-back (amplification ~1). Strips dst bits on write.
// ---------------------------------------------------------------------------
__global__ __launch_bounds__(1024) void k_place_b(const int* __restrict__ binstart,
                                                  const uint2* __restrict__ entriesA,
                                                  const int* __restrict__ nstart,
                                                  uint2* __restrict__ entries2) {
    __shared__ int cur[1024];
    const int tid = threadIdx.x;
    const int b   = blockIdx.x;
    const int n0  = b << 10;
    const int nn  = min(1024, NN2 - n0);
    if (tid < nn) cur[tid] = nstart[n0 + tid];
    __syncthreads();
    const int s0  = binstart[b];
    const int cnt = binstart[b + 1] - s0;
    for (int k = tid; k < cnt; k += 1024) {
        const uint2 a = entriesA[s0 + k];
        const int p = atomicAdd(&cur[a.x >> 17], 1);
        entries2[p] = make_uint2(a.x & 0x1FFFFu, a.y);
    }
}

// ---------------------------------------------------------------------------
// K4 (aggregate + MFMA finalize). Unchanged from R5 (passing, absmax 0.031).
// ---------------------------------------------------------------------------
__global__ __launch_bounds__(256, 8) void k_bucket(
    const uint2* __restrict__ feat16u2,
    const float* __restrict__ feat32,
    const int* __restrict__ nstart,
    const uint2* __restrict__ entries2,
    const unsigned short* __restrict__ W16,
    const float* __restrict__ bias,
    float* __restrict__ out) {
    __shared__ __align__(16) float aggrow[BN * 68];   // 17.4 KB f32
    __shared__ int hh[BN], st[BN];
    const int tid = threadIdx.x;
    const int b   = blockIdx.x;

    if (tid < BN) {
        const int s = nstart[b * BN + tid];
        const int e = nstart[b * BN + tid + 1];
        st[tid] = s;
        hh[tid] = e - s;
    }
    __syncthreads();

    // P4: aggregate — single acc, 4 lane-groups, stride 4, unroll x2.
    const int wave = tid >> 6, lane = tid & 63;
    const int group = lane >> 4, gl = lane & 15;
    for (int t = 0; t < 16; ++t) {
        const int dl  = wave * 16 + t;
        const int ss  = st[dl];
        const int deg = hh[dl];
        const int se  = ss + deg;
        float4 acc = make_float4(0.f, 0.f, 0.f, 0.f);
        int e = ss + group;
        for (; e + 4 < se; e += 8) {
            const uint2 en0 = entries2[e];
            const uint2 en1 = entries2[e + 4];
            const uint2 p0  = feat16u2[(size_t)en0.x * 16 + gl];
            const uint2 p1  = feat16u2[(size_t)en1.x * 16 + gl];
            const float w0  = __uint_as_float(en0.y);
            const float w1  = __uint_as_float(en1.y);
            acc.x = fmaf(__uint_as_float(p0.x << 16),         w0, acc.x);
            acc.y = fmaf(__uint_as_float(p0.x & 0xFFFF0000u), w0, acc.y);
            acc.z = fmaf(__uint_as_float(p0.y << 16),         w0, acc.z);
            acc.w = fmaf(__uint_as_float(p0.y & 0xFFFF0000u), w0, acc.w);
            acc.x = fmaf(__uint_as_float(p1.x << 16),         w1, acc.x);
            acc.y = fmaf(__uint_as_float(p1.x & 0xFFFF0000u), w1, acc.y);
            acc.z = fmaf(__uint_as_float(p1.y << 16),         w1, acc.z);
            acc.w = fmaf(__uint_as_float(p1.y & 0xFFFF0000u), w1, acc.w);
        }
        if (e < se) {
            const uint2 en = entries2[e];
            const float w  = __uint_as_float(en.y);
            const uint2 p  = feat16u2[(size_t)en.x * 16 + gl];
            acc.x = fmaf(__uint_as_float(p.x << 16),         w, acc.x);
            acc.y = fmaf(__uint_as_float(p.x & 0xFFFF0000u), w, acc.y);
            acc.z = fmaf(__uint_as_float(p.y << 16),         w, acc.z);
            acc.w = fmaf(__uint_as_float(p.y & 0xFFFF0000u), w, acc.w);
        }
#pragma unroll
        for (int m = 16; m <= 32; m <<= 1) {
            acc.x += __shfl_xor(acc.x, m);
            acc.y += __shfl_xor(acc.y, m);
            acc.z += __shfl_xor(acc.z, m);
            acc.w += __shfl_xor(acc.w, m);
        }
        if (group == 0) {
            const float inv = 1.0f / fmaxf((float)deg, 1.0f);
            float4 o = make_float4(acc.x * inv, acc.y * inv, acc.z * inv, acc.w * inv);
            *(float4*)&aggrow[dl * 68 + gl * 4] = o;
        }
    }
    __syncthreads();

    // P5: MFMA finalize with hi/lo split operands (near-f32 numerics).
    const int quad = lane >> 4, r = lane & 15;
    const int node0 = b * BN + wave * 16;
    int arow = node0 + r;
    if (arow > N_NODES - 1) arow = N_NODES - 1;

    bf16x8 ahi[4], alo[4];
    {
        const float* fp = &feat32[(size_t)arow * 64 + quad * 8];
        split8(*(const float4*)fp,        *(const float4*)(fp + 4),  ahi[0], alo[0]);
        split8(*(const float4*)(fp + 32), *(const float4*)(fp + 36), ahi[1], alo[1]);
        const float* ap = &aggrow[(wave * 16 + r) * 68 + quad * 8];
        split8(*(const float4*)ap,        *(const float4*)(ap + 4),  ahi[2], alo[2]);
        split8(*(const float4*)(ap + 32), *(const float4*)(ap + 36), ahi[3], alo[3]);
    }

    const unsigned short* W16lo = W16 + D * 128;
    f32x4 acc4[4] = {};
#pragma unroll
    for (int nt = 0; nt < 4; ++nt) {
#pragma unroll
        for (int kc = 0; kc < 4; ++kc) {
            const size_t wo = (size_t)(nt * 16 + r) * 128 + kc * 32 + quad * 8;
            const bf16x8 bhi = *(const bf16x8*)&W16[wo];
            const bf16x8 blo = *(const bf16x8*)&W16lo[wo];
            acc4[nt] = __builtin_amdgcn_mfma_f32_16x16x32_bf16(ahi[kc], bhi, acc4[nt], 0, 0, 0);
            acc4[nt] = __builtin_amdgcn_mfma_f32_16x16x32_bf16(alo[kc], bhi, acc4[nt], 0, 0, 0);
            acc4[nt] = __builtin_amdgcn_mfma_f32_16x16x32_bf16(ahi[kc], blo, acc4[nt], 0, 0, 0);
        }
    }

#pragma unroll
    for (int nt = 0; nt < 4; ++nt) {
        const float bv = bias[nt * 16 + r];
#pragma unroll
        for (int reg = 0; reg < 4; ++reg) {
            const int m = node0 + quad * 4 + reg;
            if (m < N_NODES) out[(size_t)m * 64 + nt * 16 + r] = acc4[nt][reg] + bv;
        }
    }
}

// ---------------------------------------------------------------------------
// Fallback path (R1): atomic scatter + shuffle finalize, if ws is too small.
// ---------------------------------------------------------------------------
__global__ __launch_bounds__(256) void fb_zero(float4* __restrict__ out4,
                                               float* __restrict__ deg) {
    const int stride = gridDim.x * blockDim.x;
    int i = blockIdx.x * blockDim.x + threadIdx.x;
    const int total4 = (N_NODES * D) / 4;
    for (int idx = i; idx < total4; idx += stride)
        out4[idx] = make_float4(0.f, 0.f, 0.f, 0.f);
    for (int idx = i; idx < N_NODES; idx += stride)
        deg[idx] = 0.f;
}

__global__ __launch_bounds__(256) void fb_scatter(
    const float* __restrict__ feat, const int* __restrict__ src,
    const int* __restrict__ dst, const float* __restrict__ ew,
    float* __restrict__ out, float* __restrict__ deg) {
    const int gid  = blockIdx.x * blockDim.x + threadIdx.x;
    const int e    = gid >> 6;
    const int lane = gid & 63;
    if (e >= N_EDGES) return;
    atomicAdd(&out[(size_t)dst[e] * D + lane], feat[(size_t)src[e] * D + lane] * ew[e]);
    if (lane == 0) atomicAdd(&deg[dst[e]], 1.0f);
}

__global__ __launch_bounds__(256) void fb_finalize(
    const float* __restrict__ feat, const float* __restrict__ Wn,
    const float* __restrict__ Ws, const float* __restrict__ bias,
    const float* __restrict__ deg, float* __restrict__ out) {
    __shared__ float lWn[D * 65];
    __shared__ float lWs[D * 65];
    for (int idx = threadIdx.x; idx < D * D; idx += 256) {
        const int r = idx >> 6, c = idx & 63;
        lWn[r * 65 + c] = Wn[idx];
        lWs[r * 65 + c] = Ws[idx];
    }
    __syncthreads();
    const int wave = threadIdx.x >> 6;
    const int lane = threadIdx.x & 63;
    const int n = blockIdx.x * 4 + wave;
    if (n >= N_NODES) return;
    const float f  = feat[(size_t)n * D + lane];
    const float sv = out[(size_t)n * D + lane];
    const float inv = 1.0f / fmaxf(deg[n], 1.0f);
    float acc_s = 0.f, acc_n = 0.f;
#pragma unroll
    for (int k = 0; k < D; ++k) {
        acc_s += __shfl(f, k)  * lWs[lane * 65 + k];
        acc_n += __shfl(sv, k) * lWn[lane * 65 + k];
    }
    out[(size_t)n * D + lane] = acc_s + acc_n * inv + bias[lane];
}

// ---------------------------------------------------------------------------
extern "C" void kernel_launch(void* const* d_in, const int* in_sizes, int n_in,
                              void* d_out, int out_size, void* d_ws, size_t ws_size,
                              hipStream_t stream) {
    const float* feat = (const float*)d_in[0];
    const int*   src  = (const int*)  d_in[1];
    const int*   dst  = (const int*)  d_in[2];
    const float* ew   = (const float*)d_in[3];
    const float* Wn   = (const float*)d_in[4];
    const float* Ws   = (const float*)d_in[5];
    const float* bias = (const float*)d_in[6];
    float* out = (float*)d_out;
    char* ws = (char*)d_ws;

    if (ws_size >= WS_NEEDED) {
        int* ncnt     = (int*)(ws + OFF_NCNT);
        int* nstart   = (int*)(ws + OFF_NSTART);
        int* bincnt   = (int*)(ws + OFF_BINCNT);
        int* binstart = (int*)(ws + OFF_BINSTART);
        int* bincur   = (int*)(ws + OFF_BINCUR);
        int* tmp      = (int*)(ws + OFF_TMP);
        int* bsum     = (int*)(ws + OFF_BSUM);
        unsigned short* W16    = (unsigned short*)(ws + OFF_W16);
        unsigned short* feat16 = (unsigned short*)(ws + OFF_FEAT16);
        uint2* entries2 = (uint2*)(ws + OFF_ENT2);
        uint2* entriesA = (uint2*)(ws + OFF_ENTA);

        k_zero     <<<(NN2 + 255) / 256, 256, 0, stream>>>(ncnt, bincnt);
        k_pre      <<<NCVT + NCNTB + 1, 256, 0, stream>>>((const float4*)feat, feat16,
                                                          Wn, Ws, W16, dst, bincnt);
        k_scan_bins<<<1, 128, 0, stream>>>(bincnt, binstart, bincur);
        k_place_a  <<<NPA, 256, 0, stream>>>(src, dst, ew, ncnt, bincur, entriesA);
        k_scan_a   <<<NSB, 1024, 0, stream>>>(ncnt, tmp, bsum);
        k_scan_b   <<<1, 128, 0, stream>>>(bsum);
        k_scan_c   <<<NSB, 1024, 0, stream>>>(tmp, bsum, nstart);
        k_place_b  <<<NBINS, 1024, 0, stream>>>(binstart, entriesA, nstart, entries2);
        k_bucket   <<<NBUCK, 256, 0, stream>>>((const uint2*)feat16, feat, nstart,
                                               entries2, W16, bias, out);
    } else {
        float* deg = (float*)d_ws;
        fb_zero<<<2048, 256, 0, stream>>>((float4*)out, deg);
        fb_scatter<<<(N_EDGES * 64) / 256, 256, 0, stream>>>(feat, src, dst, ew, out, deg);
        fb_finalize<<<(N_NODES + 3) / 4, 256, 0, stream>>>(feat, Wn, Ws, bias, deg, out);
    }
}

// Round 8
// 246.546 us; speedup vs baseline: 2.4738x; 1.2465x over previous
//
#include <hip/hip_runtime.h>
#include <hip/hip_fp16.h>

// Problem constants (from reference)
constexpr int N_NODES = 100000;
constexpr int N_EDGES = 1600000;
constexpr int D = 64;          // D_IN == D_OUT == 64

// Bucketing: 64 consecutive dst nodes per bucket (one k_bucket block each).
constexpr int BSH    = 6;
constexpr int BN     = 1 << BSH;                              // 64
constexpr int NBUCK  = (N_NODES + BN - 1) / BN;               // 1563
constexpr int NN2    = NBUCK * BN;                            // 100032 (padded nodes)
constexpr int NCNTB  = 800;                                   // bin-hist blocks
constexpr int EPB2   = N_EDGES / NCNTB;                       // 2000 (exact)
constexpr int NCVT   = (N_NODES * D / 4) / 256;               // 6250 cvt blocks
constexpr int NSB    = (NN2 + 1 + 1023) / 1024;               // 98 scan blocks
constexpr int NBINS  = (NN2 + 1023) >> 10;                    // 98 coarse bins (1024 nodes)
constexpr int CHUNK  = 2048;                                  // pass-A edges per block
constexpr int NPA    = (N_EDGES + CHUNK - 1) / CHUNK;         // 782 pass-A blocks

// ---------------------------------------------------------------------------
// Workspace layout (bytes). Total 40,034,816 <= 40,280,064 (verified avail).
// Two-pass binned counting sort; per-node counts from binned entries (k_hist).
// ---------------------------------------------------------------------------
constexpr size_t OFF_NCNT     = 0;                             // NN2 ints
constexpr size_t OFF_NSTART   = 400384;                        // NN2+1 ints
constexpr size_t OFF_BINCNT   = 800768;                        // NBINS ints
constexpr size_t OFF_BINSTART = 801280;                        // NBINS+1 ints
constexpr size_t OFF_BINCUR   = 801792;                        // NBINS ints
constexpr size_t OFF_TMP      = 1201152;                       // NN2+1 ints (local scans)
constexpr size_t OFF_BSUM     = 1601536;                       // NSB ints
constexpr size_t OFF_W16      = 1602048;                       // 32 KB (hi+lo planes)
constexpr size_t OFF_FEAT16   = 1634816;                       // N_NODES*64 fp16
constexpr size_t OFF_ENT2     = OFF_FEAT16 + (size_t)N_NODES * D * 2;  // 14,434,816
constexpr size_t OFF_ENTA     = OFF_ENT2 + (size_t)N_EDGES * 8;        // 27,234,816
constexpr size_t WS_NEEDED    = OFF_ENTA + (size_t)N_EDGES * 8;        // 40,034,816

typedef short  bf16x8 __attribute__((ext_vector_type(8)));
typedef float  f32x4  __attribute__((ext_vector_type(4)));

__device__ __forceinline__ unsigned short f2bf(float f) {   // RNE f32 -> bf16
    unsigned u = __float_as_uint(f);
    u += 0x7fffu + ((u >> 16) & 1u);
    return (unsigned short)(u >> 16);
}

// fp16 unpack helpers (gather path: 11-bit mantissa, 8x less quant error than bf16)
__device__ __forceinline__ float h2f_lo(unsigned u) {
    return __half2float(__ushort_as_half((unsigned short)(u & 0xFFFFu)));
}
__device__ __forceinline__ float h2f_hi(unsigned u) {
    return __half2float(__ushort_as_half((unsigned short)(u >> 16)));
}

// Split 8 consecutive f32 into hi/lo bf16 fragments (hi = RNE(f), lo = RNE(f - hi)).
// Residual after the split is ~2^-16 relative: near-f32 via 3-product MFMA.
__device__ __forceinline__ void split8(float4 p0, float4 p1, bf16x8& hi, bf16x8& lo) {
    float f[8] = {p0.x, p0.y, p0.z, p0.w, p1.x, p1.y, p1.z, p1.w};
#pragma unroll
    for (int i = 0; i < 8; ++i) {
        const unsigned short h = f2bf(f[i]);
        const float hf = __uint_as_float((unsigned)h << 16);
        hi[i] = (short)h;
        lo[i] = (short)f2bf(f[i] - hf);   // f - hf is exact in f32 (Sterbenz)
    }
}

// ---------------------------------------------------------------------------
// K0: zero the per-bin counters (ws is poisoned before every launch).
// ncnt no longer needs zeroing: k_hist fully overwrites it.
// ---------------------------------------------------------------------------
__global__ __launch_bounds__(256) void k_zero(int* __restrict__ bincnt) {
    int i = blockIdx.x * 256 + threadIdx.x;
    if (i < NBINS) bincnt[i] = 0;
}

// ---------------------------------------------------------------------------
// K1 (fused): blocks [0,NCVT) convert feat f32->fp16; [NCVT,NCVT+NCNTB)
// LDS bin-level histogram (98 counters) -> global bincnt; last block builds
// combined W16 hi plane [j][k] (k<64=W_self, k>=64=W_neigh) AND lo plane.
// ---------------------------------------------------------------------------
__global__ __launch_bounds__(256) void k_pre(const float4* __restrict__ feat4,
                                             unsigned short* __restrict__ feat16,
                                             const float* __restrict__ Wn,
                                             const float* __restrict__ Ws,
                                             unsigned short* __restrict__ W16,
                                             const int* __restrict__ dst,
                                             int* __restrict__ bincnt) {
    __shared__ int l[NBINS];
    const int b   = blockIdx.x;
    const int tid = threadIdx.x;
    if (b < NCVT) {
        const int i = b * 256 + tid;
        float4 v = feat4[i];
        ushort4 o;
        o.x = __half_as_ushort(__float2half_rn(v.x));
        o.y = __half_as_ushort(__float2half_rn(v.y));
        o.z = __half_as_ushort(__float2half_rn(v.z));
        o.w = __half_as_ushort(__float2half_rn(v.w));
        *(ushort4*)&feat16[(size_t)i * 4] = o;
    } else if (b < NCVT + NCNTB) {
        for (int i = tid; i < NBINS; i += 256) l[i] = 0;
        __syncthreads();
        const int base = (b - NCVT) * EPB2;
        for (int k = tid; k < EPB2; k += 256)
            atomicAdd(&l[dst[base + k] >> 10], 1);
        __syncthreads();
        for (int i = tid; i < NBINS; i += 256)
            if (l[i]) atomicAdd(&bincnt[i], l[i]);
    } else {
        for (int e = tid; e < D * 128; e += 256) {
            const int j = e >> 7, k = e & 127;
            const float w = (k < D) ? Ws[j * D + k] : Wn[j * D + (k - D)];
            const unsigned short h = f2bf(w);
            const float hf = __uint_as_float((unsigned)h << 16);
            W16[e] = h;
            W16[D * 128 + e] = f2bf(w - hf);
        }
    }
}

// ---------------------------------------------------------------------------
// K2bin: tiny exclusive scan of 98 bin counts -> binstart (+sentinel), bincur.
// ---------------------------------------------------------------------------
__global__ __launch_bounds__(128) void k_scan_bins(const int* __restrict__ bincnt,
                                                   int* __restrict__ binstart,
                                                   int* __restrict__ bincur) {
    __shared__ int s[128];
    const int t = threadIdx.x;
    const int v = (t < NBINS) ? bincnt[t] : 0;
    s[t] = v;
    __syncthreads();
    for (int off = 1; off < 128; off <<= 1) {
        int u = (t >= off) ? s[t - off] : 0;
        __syncthreads();
        s[t] += u;
        __syncthreads();
    }
    if (t < NBINS) { binstart[t] = s[t] - v; bincur[t] = s[t] - v; }
    if (t == 0) binstart[NBINS] = N_EDGES;
}

// ---------------------------------------------------------------------------
// K3a: pass A — LDS-staged partition of edges into 98 coarse bins. CHUNK=2048
// (782 blocks, ~20KB LDS) for grid-level parallelism (R7: 196 blocks @ 7.8%
// occupancy was the bottleneck). No global ncnt atomics (moved to k_hist).
// entriesA.x = src | (dst&1023)<<17.
// ---------------------------------------------------------------------------
__global__ __launch_bounds__(256) void k_place_a(const int* __restrict__ src,
                                                 const int* __restrict__ dst,
                                                 const float* __restrict__ ew,
                                                 int* __restrict__ bincur,
                                                 uint2* __restrict__ entriesA) {
    __shared__ __align__(16) uint2 stage[CHUNK];       // 16 KB
    __shared__ unsigned char sbin[CHUNK];              // 2 KB
    __shared__ int hist[NBINS], lstart[NBINS], lcur[NBINS], gbase[NBINS];
    __shared__ int s[256];
    const int tid = threadIdx.x;
    const int e0  = blockIdx.x * CHUNK;
    const int cnt = min(CHUNK, N_EDGES - e0);

    for (int i = tid; i < NBINS; i += 256) hist[i] = 0;
    __syncthreads();
    for (int k = tid; k < cnt; k += 256)
        atomicAdd(&hist[dst[e0 + k] >> 10], 1);
    __syncthreads();
    // block-local exclusive scan of 98 bin counts (256-wide Hillis-Steele)
    {
        const int v = (tid < NBINS) ? hist[tid] : 0;
        s[tid] = v;
        __syncthreads();
        for (int off = 1; off < 256; off <<= 1) {
            int u = (tid >= off) ? s[tid - off] : 0;
            __syncthreads();
            s[tid] += u;
            __syncthreads();
        }
        if (tid < NBINS) {
            const int ex = s[tid] - v;
            lstart[tid] = ex;
            lcur[tid]   = ex;
            gbase[tid]  = v ? atomicAdd(&bincur[tid], v) : 0;
        }
    }
    __syncthreads();
    // stage entries into LDS grouped by bin
    for (int k = tid; k < cnt; k += 256) {
        const int d = dst[e0 + k];
        const int b = d >> 10;
        const int p = atomicAdd(&lcur[b], 1);
        stage[p] = make_uint2((unsigned)src[e0 + k] | ((unsigned)(d & 1023) << 17),
                              __float_as_uint(ew[e0 + k]));
        sbin[p]  = (unsigned char)b;
    }
    __syncthreads();
    // flush: consecutive slots -> consecutive global addresses per bin run
    for (int j = tid; j < cnt; j += 256) {
        const int b = sbin[j];
        entriesA[gbase[b] + (j - lstart[b])] = stage[j];
    }
}

// ---------------------------------------------------------------------------
// K3h (NEW): per-bin LDS histogram from binned entriesA -> coalesced ncnt
// writes. Replaces 1.6M global ncnt atomics (R7's ~50MB write-amp source).
// ---------------------------------------------------------------------------
__global__ __launch_bounds__(1024) void k_hist(const int* __restrict__ binstart,
                                               const uint2* __restrict__ entriesA,
                                               int* __restrict__ ncnt) {
    __shared__ int h[1024];
    const int tid = threadIdx.x;
    const int b   = blockIdx.x;
    h[tid] = 0;
    __syncthreads();
    const int s0  = binstart[b];
    const int cnt = binstart[b + 1] - s0;
    for (int k = tid; k < cnt; k += 1024)
        atomicAdd(&h[entriesA[s0 + k].x >> 17], 1);
    __syncthreads();
    const int n = (b << 10) + tid;
    if (n < NN2) ncnt[n] = h[tid];
}

// ---------------------------------------------------------------------------
// K2a/b/c: hierarchical exclusive scan of NN2+1 per-node counts (R5-verified).
// ---------------------------------------------------------------------------
__global__ __launch_bounds__(1024) void k_scan_a(const int* __restrict__ ncnt,
                                                 int* __restrict__ tmp,
                                                 int* __restrict__ bsum) {
    __shared__ int s[1024];
    const int t   = threadIdx.x;
    const int gid = blockIdx.x * 1024 + t;
    const int v   = (gid < NN2) ? ncnt[gid] : 0;
    s[t] = v;
    __syncthreads();
    for (int off = 1; off < 1024; off <<= 1) {
        int u = (t >= off) ? s[t - off] : 0;
        __syncthreads();
        s[t] += u;
        __syncthreads();
    }
    if (gid <= NN2) tmp[gid] = s[t] - v;     // block-local exclusive
    if (t == 1023) bsum[blockIdx.x] = s[t];  // block total
}

__global__ __launch_bounds__(128) void k_scan_b(int* __restrict__ bsum) {
    __shared__ int s[128];
    const int t = threadIdx.x;
    const int v = (t < NSB) ? bsum[t] : 0;
    s[t] = v;
    __syncthreads();
    for (int off = 1; off < 128; off <<= 1) {
        int u = (t >= off) ? s[t - off] : 0;
        __syncthreads();
        s[t] += u;
        __syncthreads();
    }
    if (t < NSB) bsum[t] = s[t] - v;         // exclusive block offsets
}

__global__ __launch_bounds__(1024) void k_scan_c(const int* __restrict__ tmp,
                                                 const int* __restrict__ bsum,
                                                 int* __restrict__ nstart) {
    const int gid = blockIdx.x * 1024 + threadIdx.x;
    if (gid <= NN2) nstart[gid] = tmp[gid] + bsum[blockIdx.x];
}

// ---------------------------------------------------------------------------
// K3b: pass B — one 1024-thread block per bin (single CU => single XCD).
// Per-node cursors in LDS (absolute positions seeded from nstart); scattered
// writes span only the bin's ~130KB window inside ONE L2 -> lines fully
// accumulate before write-back. Strips dst bits on write.
// ---------------------------------------------------------------------------
__global__ __launch_bounds__(1024) void k_place_b(const int* __restrict__ binstart,
                                                  const uint2* __restrict__ entriesA,
                                                  const int* __restrict__ nstart,
                                                  uint2* __restrict__ entries2) {
    __shared__ int cur[1024];
    const int tid = threadIdx.x;
    const int b   = blockIdx.x;
    const int n0  = b << 10;
    const int nn  = min(1024, NN2 - n0);
    if (tid < nn) cur[tid] = nstart[n0 + tid];
    __syncthreads();
    const int s0  = binstart[b];
    const int cnt = binstart[b + 1] - s0;
    for (int k = tid; k < cnt; k += 1024) {
        const uint2 a = entriesA[s0 + k];
        const int p = atomicAdd(&cur[a.x >> 17], 1);
        entries2[p] = make_uint2(a.x & 0x1FFFFu, a.y);
    }
}

// ---------------------------------------------------------------------------
// K4 (aggregate + MFMA finalize). P4 gather now unpacks fp16 (8x less quant
// error than bf16 -> absmax margin safe under any edge ordering). Structure
// unchanged from the passing R5/R7 versions (f32 aggrow, split MFMA).
// ---------------------------------------------------------------------------
__global__ __launch_bounds__(256, 8) void k_bucket(
    const uint2* __restrict__ feat16u2,
    const float* __restrict__ feat32,
    const int* __restrict__ nstart,
    const uint2* __restrict__ entries2,
    const unsigned short* __restrict__ W16,
    const float* __restrict__ bias,
    float* __restrict__ out) {
    __shared__ __align__(16) float aggrow[BN * 68];   // 17.4 KB f32
    __shared__ int hh[BN], st[BN];
    const int tid = threadIdx.x;
    const int b   = blockIdx.x;

    if (tid < BN) {
        const int s = nstart[b * BN + tid];
        const int e = nstart[b * BN + tid + 1];
        st[tid] = s;
        hh[tid] = e - s;
    }
    __syncthreads();

    // P4: aggregate — single acc, 4 lane-groups, stride 4, unroll x2.
    const int wave = tid >> 6, lane = tid & 63;
    const int group = lane >> 4, gl = lane & 15;
    for (int t = 0; t < 16; ++t) {
        const int dl  = wave * 16 + t;
        const int ss  = st[dl];
        const int deg = hh[dl];
        const int se  = ss + deg;
        float4 acc = make_float4(0.f, 0.f, 0.f, 0.f);
        int e = ss + group;
        for (; e + 4 < se; e += 8) {
            const uint2 en0 = entries2[e];
            const uint2 en1 = entries2[e + 4];
            const uint2 p0  = feat16u2[(size_t)en0.x * 16 + gl];
            const uint2 p1  = feat16u2[(size_t)en1.x * 16 + gl];
            const float w0  = __uint_as_float(en0.y);
            const float w1  = __uint_as_float(en1.y);
            acc.x = fmaf(h2f_lo(p0.x), w0, acc.x);
            acc.y = fmaf(h2f_hi(p0.x), w0, acc.y);
            acc.z = fmaf(h2f_lo(p0.y), w0, acc.z);
            acc.w = fmaf(h2f_hi(p0.y), w0, acc.w);
            acc.x = fmaf(h2f_lo(p1.x), w1, acc.x);
            acc.y = fmaf(h2f_hi(p1.x), w1, acc.y);
            acc.z = fmaf(h2f_lo(p1.y), w1, acc.z);
            acc.w = fmaf(h2f_hi(p1.y), w1, acc.w);
        }
        if (e < se) {
            const uint2 en = entries2[e];
            const float w  = __uint_as_float(en.y);
            const uint2 p  = feat16u2[(size_t)en.x * 16 + gl];
            acc.x = fmaf(h2f_lo(p.x), w, acc.x);
            acc.y = fmaf(h2f_hi(p.x), w, acc.y);
            acc.z = fmaf(h2f_lo(p.y), w, acc.z);
            acc.w = fmaf(h2f_hi(p.y), w, acc.w);
        }
#pragma unroll
        for (int m = 16; m <= 32; m <<= 1) {
            acc.x += __shfl_xor(acc.x, m);
            acc.y += __shfl_xor(acc.y, m);
            acc.z += __shfl_xor(acc.z, m);
            acc.w += __shfl_xor(acc.w, m);
        }
        if (group == 0) {
            const float inv = 1.0f / fmaxf((float)deg, 1.0f);
            float4 o = make_float4(acc.x * inv, acc.y * inv, acc.z * inv, acc.w * inv);
            *(float4*)&aggrow[dl * 68 + gl * 4] = o;
        }
    }
    __syncthreads();

    // P5: MFMA finalize with hi/lo split operands (near-f32 numerics).
    const int quad = lane >> 4, r = lane & 15;
    const int node0 = b * BN + wave * 16;
    int arow = node0 + r;
    if (arow > N_NODES - 1) arow = N_NODES - 1;

    bf16x8 ahi[4], alo[4];
    {
        const float* fp = &feat32[(size_t)arow * 64 + quad * 8];
        split8(*(const float4*)fp,        *(const float4*)(fp + 4),  ahi[0], alo[0]);
        split8(*(const float4*)(fp + 32), *(const float4*)(fp + 36), ahi[1], alo[1]);
        const float* ap = &aggrow[(wave * 16 + r) * 68 + quad * 8];
        split8(*(const float4*)ap,        *(const float4*)(ap + 4),  ahi[2], alo[2]);
        split8(*(const float4*)(ap + 32), *(const float4*)(ap + 36), ahi[3], alo[3]);
    }

    const unsigned short* W16lo = W16 + D * 128;
    f32x4 acc4[4] = {};
#pragma unroll
    for (int nt = 0; nt < 4; ++nt) {
#pragma unroll
        for (int kc = 0; kc < 4; ++kc) {
            const size_t wo = (size_t)(nt * 16 + r) * 128 + kc * 32 + quad * 8;
            const bf16x8 bhi = *(const bf16x8*)&W16[wo];
            const bf16x8 blo = *(const bf16x8*)&W16lo[wo];
            acc4[nt] = __builtin_amdgcn_mfma_f32_16x16x32_bf16(ahi[kc], bhi, acc4[nt], 0, 0, 0);
            acc4[nt] = __builtin_amdgcn_mfma_f32_16x16x32_bf16(alo[kc], bhi, acc4[nt], 0, 0, 0);
            acc4[nt] = __builtin_amdgcn_mfma_f32_16x16x32_bf16(ahi[kc], blo, acc4[nt], 0, 0, 0);
        }
    }

#pragma unroll
    for (int nt = 0; nt < 4; ++nt) {
        const float bv = bias[nt * 16 + r];
#pragma unroll
        for (int reg = 0; reg < 4; ++reg) {
            const int m = node0 + quad * 4 + reg;
            if (m < N_NODES) out[(size_t)m * 64 + nt * 16 + r] = acc4[nt][reg] + bv;
        }
    }
}

// ---------------------------------------------------------------------------
// Fallback path (R1): atomic scatter + shuffle finalize, if ws is too small.
// ---------------------------------------------------------------------------
__global__ __launch_bounds__(256) void fb_zero(float4* __restrict__ out4,
                                               float* __restrict__ deg) {
    const int stride = gridDim.x * blockDim.x;
    int i = blockIdx.x * blockDim.x + threadIdx.x;
    const int total4 = (N_NODES * D) / 4;
    for (int idx = i; idx < total4; idx += stride)
        out4[idx] = make_float4(0.f, 0.f, 0.f, 0.f);
    for (int idx = i; idx < N_NODES; idx += stride)
        deg[idx] = 0.f;
}

__global__ __launch_bounds__(256) void fb_scatter(
    const float* __restrict__ feat, const int* __restrict__ src,
    const int* __restrict__ dst, const float* __restrict__ ew,
    float* __restrict__ out, float* __restrict__ deg) {
    const int gid  = blockIdx.x * blockDim.x + threadIdx.x;
    const int e    = gid >> 6;
    const int lane = gid & 63;
    if (e >= N_EDGES) return;
    atomicAdd(&out[(size_t)dst[e] * D + lane], feat[(size_t)src[e] * D + lane] * ew[e]);
    if (lane == 0) atomicAdd(&deg[dst[e]], 1.0f);
}

__global__ __launch_bounds__(256) void fb_finalize(
    const float* __restrict__ feat, const float* __restrict__ Wn,
    const float* __restrict__ Ws, const float* __restrict__ bias,
    const float* __restrict__ deg, float* __restrict__ out) {
    __shared__ float lWn[D * 65];
    __shared__ float lWs[D * 65];
    for (int idx = threadIdx.x; idx < D * D; idx += 256) {
        const int r = idx >> 6, c = idx & 63;
        lWn[r * 65 + c] = Wn[idx];
        lWs[r * 65 + c] = Ws[idx];
    }
    __syncthreads();
    const int wave = threadIdx.x >> 6;
    const int lane = threadIdx.x & 63;
    const int n = blockIdx.x * 4 + wave;
    if (n >= N_NODES) return;
    const float f  = feat[(size_t)n * D + lane];
    const float sv = out[(size_t)n * D + lane];
    const float inv = 1.0f / fmaxf(deg[n], 1.0f);
    float acc_s = 0.f, acc_n = 0.f;
#pragma unroll
    for (int k = 0; k < D; ++k) {
        acc_s += __shfl(f, k)  * lWs[lane * 65 + k];
        acc_n += __shfl(sv, k) * lWn[lane * 65 + k];
    }
    out[(size_t)n * D + lane] = acc_s + acc_n * inv + bias[lane];
}

// ---------------------------------------------------------------------------
extern "C" void kernel_launch(void* const* d_in, const int* in_sizes, int n_in,
                              void* d_out, int out_size, void* d_ws, size_t ws_size,
                              hipStream_t stream) {
    const float* feat = (const float*)d_in[0];
    const int*   src  = (const int*)  d_in[1];
    const int*   dst  = (const int*)  d_in[2];
    const float* ew   = (const float*)d_in[3];
    const float* Wn   = (const float*)d_in[4];
    const float* Ws   = (const float*)d_in[5];
    const float* bias = (const float*)d_in[6];
    float* out = (float*)d_out;
    char* ws = (char*)d_ws;

    if (ws_size >= WS_NEEDED) {
        int* ncnt     = (int*)(ws + OFF_NCNT);
        int* nstart   = (int*)(ws + OFF_NSTART);
        int* bincnt   = (int*)(ws + OFF_BINCNT);
        int* binstart = (int*)(ws + OFF_BINSTART);
        int* bincur   = (int*)(ws + OFF_BINCUR);
        int* tmp      = (int*)(ws + OFF_TMP);
        int* bsum     = (int*)(ws + OFF_BSUM);
        unsigned short* W16    = (unsigned short*)(ws + OFF_W16);
        unsigned short* feat16 = (unsigned short*)(ws + OFF_FEAT16);
        uint2* entries2 = (uint2*)(ws + OFF_ENT2);
        uint2* entriesA = (uint2*)(ws + OFF_ENTA);

        k_zero     <<<1, 256, 0, stream>>>(bincnt);
        k_pre      <<<NCVT + NCNTB + 1, 256, 0, stream>>>((const float4*)feat, feat16,
                                                          Wn, Ws, W16, dst, bincnt);
        k_scan_bins<<<1, 128, 0, stream>>>(bincnt, binstart, bincur);
        k_place_a  <<<NPA, 256, 0, stream>>>(src, dst, ew, bincur, entriesA);
        k_hist     <<<NBINS, 1024, 0, stream>>>(binstart, entriesA, ncnt);
        k_scan_a   <<<NSB, 1024, 0, stream>>>(ncnt, tmp, bsum);
        k_scan_b   <<<1, 128, 0, stream>>>(bsum);
        k_scan_c   <<<NSB, 1024, 0, stream>>>(tmp, bsum, nstart);
        k_place_b  <<<NBINS, 1024, 0, stream>>>(binstart, entriesA, nstart, entries2);
        k_bucket   <<<NBUCK, 256, 0, stream>>>((const uint2*)feat16, feat, nstart,
                                               entries2, W16, bias, out);
    } else {
        float* deg = (float*)d_ws;
        fb_zero<<<2048, 256, 0, stream>>>((float4*)out, deg);
        fb_scatter<<<(N_EDGES * 64) / 256, 256, 0, stream>>>(feat, src, dst, ew, out, deg);
        fb_finalize<<<(N_NODES + 3) / 4, 256, 0, stream>>>(feat, Wn, Ws, bias, deg, out);
    }
}

// Round 10
// 246.444 us; speedup vs baseline: 2.4748x; 1.0004x over previous
//
#include <hip/hip_runtime.h>
#include <hip/hip_fp16.h>

// Problem constants (from reference)
constexpr int N_NODES = 100000;
constexpr int N_EDGES = 1600000;
constexpr int D = 64;          // D_IN == D_OUT == 64

// Bucketing: 64 consecutive dst nodes per bucket (one k_bucket block each).
constexpr int BSH    = 6;
constexpr int BN     = 1 << BSH;                              // 64
constexpr int NBUCK  = (N_NODES + BN - 1) / BN;               // 1563
constexpr int NN2    = NBUCK * BN;                            // 100032 (padded nodes)
constexpr int NCNTB  = 800;                                   // bin-hist blocks
constexpr int EPB2   = N_EDGES / NCNTB;                       // 2000 (exact)
constexpr int NCVT   = (N_NODES * D / 4) / 256;               // 6250 cvt blocks
constexpr int NBINS  = (NN2 + 1023) >> 10;                    // 98 coarse bins (1024 nodes)
constexpr int CHUNK  = 2048;                                  // pass-A edges per block
constexpr int NPA    = (N_EDGES + CHUNK - 1) / CHUNK;         // 782 pass-A blocks

// ---------------------------------------------------------------------------
// Workspace layout (bytes). Total 40,034,816 <= 40,280,064 (verified avail).
// Two-pass binned counting sort; nstart built per-bin inside k_sortbin
// (bins are contiguous in node-space AND entry-space -> no global scan).
// ---------------------------------------------------------------------------
constexpr size_t OFF_NSTART   = 400384;                        // NN2+1 ints
constexpr size_t OFF_BINCNT   = 800768;                        // NBINS ints
constexpr size_t OFF_BINSTART = 801280;                        // NBINS+1 ints
constexpr size_t OFF_BINCUR   = 801792;                        // NBINS ints
constexpr size_t OFF_W16      = 1602048;                       // 32 KB (hi+lo planes)
constexpr size_t OFF_FEAT16   = 1634816;                       // N_NODES*64 fp16
constexpr size_t OFF_ENT2     = OFF_FEAT16 + (size_t)N_NODES * D * 2;  // 14,434,816
constexpr size_t OFF_ENTA     = OFF_ENT2 + (size_t)N_EDGES * 8;        // 27,234,816
constexpr size_t WS_NEEDED    = OFF_ENTA + (size_t)N_EDGES * 8;        // 40,034,816

typedef short  bf16x8 __attribute__((ext_vector_type(8)));
typedef float  f32x4  __attribute__((ext_vector_type(4)));

__device__ __forceinline__ unsigned short f2bf(float f) {   // RNE f32 -> bf16
    unsigned u = __float_as_uint(f);
    u += 0x7fffu + ((u >> 16) & 1u);
    return (unsigned short)(u >> 16);
}

// fp16 unpack helpers (gather path: 11-bit mantissa, 8x less quant error than bf16)
__device__ __forceinline__ float h2f_lo(unsigned u) {
    return __half2float(__ushort_as_half((unsigned short)(u & 0xFFFFu)));
}
__device__ __forceinline__ float h2f_hi(unsigned u) {
    return __half2float(__ushort_as_half((unsigned short)(u >> 16)));
}

// Split 8 consecutive f32 into hi/lo bf16 fragments (hi = RNE(f), lo = RNE(f - hi)).
// Residual after the split is ~2^-16 relative: near-f32 via 3-product MFMA.
__device__ __forceinline__ void split8(float4 p0, float4 p1, bf16x8& hi, bf16x8& lo) {
    float f[8] = {p0.x, p0.y, p0.z, p0.w, p1.x, p1.y, p1.z, p1.w};
#pragma unroll
    for (int i = 0; i < 8; ++i) {
        const unsigned short h = f2bf(f[i]);
        const float hf = __uint_as_float((unsigned)h << 16);
        hi[i] = (short)h;
        lo[i] = (short)f2bf(f[i] - hf);   // f - hf is exact in f32 (Sterbenz)
    }
}

// ---------------------------------------------------------------------------
// K0: zero the per-bin counters (ws is poisoned before every launch).
// ---------------------------------------------------------------------------
__global__ __launch_bounds__(256) void k_zero(int* __restrict__ bincnt) {
    int i = blockIdx.x * 256 + threadIdx.x;
    if (i < NBINS) bincnt[i] = 0;
}

// ---------------------------------------------------------------------------
// K1 (fused): blocks [0,NCVT) convert feat f32->fp16; [NCVT,NCVT+NCNTB)
// LDS bin-level histogram (98 counters) -> global bincnt; last block builds
// combined W16 hi plane [j][k] (k<64=W_self, k>=64=W_neigh) AND lo plane.
// ---------------------------------------------------------------------------
__global__ __launch_bounds__(256) void k_pre(const float4* __restrict__ feat4,
                                             unsigned short* __restrict__ feat16,
                                             const float* __restrict__ Wn,
                                             const float* __restrict__ Ws,
                                             unsigned short* __restrict__ W16,
                                             const int* __restrict__ dst,
                                             int* __restrict__ bincnt) {
    __shared__ int l[NBINS];
    const int b   = blockIdx.x;
    const int tid = threadIdx.x;
    if (b < NCVT) {
        const int i = b * 256 + tid;
        float4 v = feat4[i];
        ushort4 o;
        o.x = __half_as_ushort(__float2half_rn(v.x));
        o.y = __half_as_ushort(__float2half_rn(v.y));
        o.z = __half_as_ushort(__float2half_rn(v.z));
        o.w = __half_as_ushort(__float2half_rn(v.w));
        *(ushort4*)&feat16[(size_t)i * 4] = o;
    } else if (b < NCVT + NCNTB) {
        for (int i = tid; i < NBINS; i += 256) l[i] = 0;
        __syncthreads();
        const int base = (b - NCVT) * EPB2;
        for (int k = tid; k < EPB2; k += 256)
            atomicAdd(&l[dst[base + k] >> 10], 1);
        __syncthreads();
        for (int i = tid; i < NBINS; i += 256)
            if (l[i]) atomicAdd(&bincnt[i], l[i]);
    } else {
        for (int e = tid; e < D * 128; e += 256) {
            const int j = e >> 7, k = e & 127;
            const float w = (k < D) ? Ws[j * D + k] : Wn[j * D + (k - D)];
            const unsigned short h = f2bf(w);
            const float hf = __uint_as_float((unsigned)h << 16);
            W16[e] = h;
            W16[D * 128 + e] = f2bf(w - hf);
        }
    }
}

// ---------------------------------------------------------------------------
// K2bin: tiny exclusive scan of 98 bin counts -> binstart (+sentinel), bincur.
// ---------------------------------------------------------------------------
__global__ __launch_bounds__(128) void k_scan_bins(const int* __restrict__ bincnt,
                                                   int* __restrict__ binstart,
                                                   int* __restrict__ bincur) {
    __shared__ int s[128];
    const int t = threadIdx.x;
    const int v = (t < NBINS) ? bincnt[t] : 0;
    s[t] = v;
    __syncthreads();
    for (int off = 1; off < 128; off <<= 1) {
        int u = (t >= off) ? s[t - off] : 0;
        __syncthreads();
        s[t] += u;
        __syncthreads();
    }
    if (t < NBINS) { binstart[t] = s[t] - v; bincur[t] = s[t] - v; }
    if (t == 0) binstart[NBINS] = N_EDGES;
}

// ---------------------------------------------------------------------------
// K3a: pass A — LDS-staged partition of edges into 98 coarse bins (R8-
// verified). entriesA.x = src | (dst&1023)<<17.
// ---------------------------------------------------------------------------
__global__ __launch_bounds__(256) void k_place_a(const int* __restrict__ src,
                                                 const int* __restrict__ dst,
                                                 const float* __restrict__ ew,
                                                 int* __restrict__ bincur,
                                                 uint2* __restrict__ entriesA) {
    __shared__ __align__(16) uint2 stage[CHUNK];       // 16 KB
    __shared__ unsigned char sbin[CHUNK];              // 2 KB
    __shared__ int hist[NBINS], lstart[NBINS], lcur[NBINS], gbase[NBINS];
    __shared__ int s[256];
    const int tid = threadIdx.x;
    const int e0  = blockIdx.x * CHUNK;
    const int cnt = min(CHUNK, N_EDGES - e0);

    for (int i = tid; i < NBINS; i += 256) hist[i] = 0;
    __syncthreads();
    for (int k = tid; k < cnt; k += 256)
        atomicAdd(&hist[dst[e0 + k] >> 10], 1);
    __syncthreads();
    // block-local exclusive scan of 98 bin counts (256-wide Hillis-Steele)
    {
        const int v = (tid < NBINS) ? hist[tid] : 0;
        s[tid] = v;
        __syncthreads();
        for (int off = 1; off < 256; off <<= 1) {
            int u = (tid >= off) ? s[tid - off] : 0;
            __syncthreads();
            s[tid] += u;
            __syncthreads();
        }
        if (tid < NBINS) {
            const int ex = s[tid] - v;
            lstart[tid] = ex;
            lcur[tid]   = ex;
            gbase[tid]  = v ? atomicAdd(&bincur[tid], v) : 0;
        }
    }
    __syncthreads();
    // stage entries into LDS grouped by bin
    for (int k = tid; k < cnt; k += 256) {
        const int d = dst[e0 + k];
        const int b = d >> 10;
        const int p = atomicAdd(&lcur[b], 1);
        stage[p] = make_uint2((unsigned)src[e0 + k] | ((unsigned)(d & 1023) << 17),
                              __float_as_uint(ew[e0 + k]));
        sbin[p]  = (unsigned char)b;
    }
    __syncthreads();
    // flush: consecutive slots -> consecutive global addresses per bin run
    for (int j = tid; j < cnt; j += 256) {
        const int b = sbin[j];
        entriesA[gbase[b] + (j - lstart[b])] = stage[j];
    }
}

// ---------------------------------------------------------------------------
// K3b (FUSED, replaces k_hist + k_scan_a/b/c + k_place_b): one 1024-thread
// block per bin. Bins are contiguous in node-space AND entry-space, so
// nstart[n] = binstart[b] + in-block exclusive scan of the bin's 1024-counter
// histogram — no global scan needed. Then place entries node-sorted (same
// thread/order pattern as R8's k_place_b => bit-identical entries2).
// ---------------------------------------------------------------------------
__global__ __launch_bounds__(1024) void k_sortbin(const int* __restrict__ binstart,
                                                  const uint2* __restrict__ entriesA,
                                                  int* __restrict__ nstart,
                                                  uint2* __restrict__ entries2) {
    __shared__ int h[1024];
    __shared__ int s[1024];
    __shared__ int cur[1024];
    const int tid = threadIdx.x;
    const int b   = blockIdx.x;
    const int s0  = binstart[b];
    const int cnt = binstart[b + 1] - s0;

    h[tid] = 0;
    __syncthreads();
    for (int k = tid; k < cnt; k += 1024)
        atomicAdd(&h[entriesA[s0 + k].x >> 17], 1);
    __syncthreads();
    // in-block exclusive scan of the 1024 per-node counts
    const int v = h[tid];
    s[tid] = v;
    __syncthreads();
    for (int off = 1; off < 1024; off <<= 1) {
        int u = (tid >= off) ? s[tid - off] : 0;
        __syncthreads();
        s[tid] += u;
        __syncthreads();
    }
    const int pos = s0 + s[tid] - v;      // absolute start of this node's run
    cur[tid] = pos;
    const int n = (b << 10) + tid;
    if (n < NN2) nstart[n] = pos;
    if (b == NBINS - 1 && tid == 0) nstart[NN2] = N_EDGES;
    __syncthreads();
    // place: bin slice is L2-warm from the histogram pass
    for (int k = tid; k < cnt; k += 1024) {
        const uint2 a = entriesA[s0 + k];
        const int p = atomicAdd(&cur[a.x >> 17], 1);
        entries2[p] = make_uint2(a.x & 0x1FFFFu, a.y);
    }
}

// ---------------------------------------------------------------------------
// K4 (aggregate + MFMA finalize). P4 edge loop unrolled x4: 4 outstanding
// entry+gather pairs per lane (R8 @ x2 was still latency-bound: VALUBusy 25%,
// MfmaUtil 2.5%, HBM 21%). Per-group summation order unchanged (e, e+4, e+8,
// e+12 sequential) => numerics identical to R8.
// ---------------------------------------------------------------------------
__global__ __launch_bounds__(256, 8) void k_bucket(
    const uint2* __restrict__ feat16u2,
    const float* __restrict__ feat32,
    const int* __restrict__ nstart,
    const uint2* __restrict__ entries2,
    const unsigned short* __restrict__ W16,
    const float* __restrict__ bias,
    float* __restrict__ out) {
    __shared__ __align__(16) float aggrow[BN * 68];   // 17.4 KB f32
    __shared__ int hh[BN], st[BN];
    const int tid = threadIdx.x;
    const int b   = blockIdx.x;

    if (tid < BN) {
        const int s = nstart[b * BN + tid];
        const int e = nstart[b * BN + tid + 1];
        st[tid] = s;
        hh[tid] = e - s;
    }
    __syncthreads();

    // P4: aggregate — single acc, 4 lane-groups, stride 4, unroll x4.
    const int wave = tid >> 6, lane = tid & 63;
    const int group = lane >> 4, gl = lane & 15;
    for (int t = 0; t < 16; ++t) {
        const int dl  = wave * 16 + t;
        const int ss  = st[dl];
        const int deg = hh[dl];
        const int se  = ss + deg;
        float4 acc = make_float4(0.f, 0.f, 0.f, 0.f);
        int e = ss + group;
        for (; e + 12 < se; e += 16) {
            const uint2 en0 = entries2[e];
            const uint2 en1 = entries2[e + 4];
            const uint2 en2 = entries2[e + 8];
            const uint2 en3 = entries2[e + 12];
            const uint2 p0  = feat16u2[(size_t)en0.x * 16 + gl];
            const uint2 p1  = feat16u2[(size_t)en1.x * 16 + gl];
            const uint2 p2  = feat16u2[(size_t)en2.x * 16 + gl];
            const uint2 p3  = feat16u2[(size_t)en3.x * 16 + gl];
            const float w0  = __uint_as_float(en0.y);
            const float w1  = __uint_as_float(en1.y);
            const float w2  = __uint_as_float(en2.y);
            const float w3  = __uint_as_float(en3.y);
            acc.x = fmaf(h2f_lo(p0.x), w0, acc.x);
            acc.y = fmaf(h2f_hi(p0.x), w0, acc.y);
            acc.z = fmaf(h2f_lo(p0.y), w0, acc.z);
            acc.w = fmaf(h2f_hi(p0.y), w0, acc.w);
            acc.x = fmaf(h2f_lo(p1.x), w1, acc.x);
            acc.y = fmaf(h2f_hi(p1.x), w1, acc.y);
            acc.z = fmaf(h2f_lo(p1.y), w1, acc.z);
            acc.w = fmaf(h2f_hi(p1.y), w1, acc.w);
            acc.x = fmaf(h2f_lo(p2.x), w2, acc.x);
            acc.y = fmaf(h2f_hi(p2.x), w2, acc.y);
            acc.z = fmaf(h2f_lo(p2.y), w2, acc.z);
            acc.w = fmaf(h2f_hi(p2.y), w2, acc.w);
            acc.x = fmaf(h2f_lo(p3.x), w3, acc.x);
            acc.y = fmaf(h2f_hi(p3.x), w3, acc.y);
            acc.z = fmaf(h2f_lo(p3.y), w3, acc.z);
            acc.w = fmaf(h2f_hi(p3.y), w3, acc.w);
        }
        for (; e < se; e += 4) {
            const uint2 en = entries2[e];
            const float w  = __uint_as_float(en.y);
            const uint2 p  = feat16u2[(size_t)en.x * 16 + gl];
            acc.x = fmaf(h2f_lo(p.x), w, acc.x);
            acc.y = fmaf(h2f_hi(p.x), w, acc.y);
            acc.z = fmaf(h2f_lo(p.y), w, acc.z);
            acc.w = fmaf(h2f_hi(p.y), w, acc.w);
        }
#pragma unroll
        for (int m = 16; m <= 32; m <<= 1) {
            acc.x += __shfl_xor(acc.x, m);
            acc.y += __shfl_xor(acc.y, m);
            acc.z += __shfl_xor(acc.z, m);
            acc.w += __shfl_xor(acc.w, m);
        }
        if (group == 0) {
            const float inv = 1.0f / fmaxf((float)deg, 1.0f);
            float4 o = make_float4(acc.x * inv, acc.y * inv, acc.z * inv, acc.w * inv);
            *(float4*)&aggrow[dl * 68 + gl * 4] = o;
        }
    }
    __syncthreads();

    // P5: MFMA finalize with hi/lo split operands (near-f32 numerics).
    const int quad = lane >> 4, r = lane & 15;
    const int node0 = b * BN + wave * 16;
    int arow = node0 + r;
    if (arow > N_NODES - 1) arow = N_NODES - 1;

    bf16x8 ahi[4], alo[4];
    {
        const float* fp = &feat32[(size_t)arow * 64 + quad * 8];
        split8(*(const float4*)fp,        *(const float4*)(fp + 4),  ahi[0], alo[0]);
        split8(*(const float4*)(fp + 32), *(const float4*)(fp + 36), ahi[1], alo[1]);
        const float* ap = &aggrow[(wave * 16 + r) * 68 + quad * 8];
        split8(*(const float4*)ap,        *(const float4*)(ap + 4),  ahi[2], alo[2]);
        split8(*(const float4*)(ap + 32), *(const float4*)(ap + 36), ahi[3], alo[3]);
    }

    const unsigned short* W16lo = W16 + D * 128;
    f32x4 acc4[4] = {};
#pragma unroll
    for (int nt = 0; nt < 4; ++nt) {
#pragma unroll
        for (int kc = 0; kc < 4; ++kc) {
            const size_t wo = (size_t)(nt * 16 + r) * 128 + kc * 32 + quad * 8;
            const bf16x8 bhi = *(const bf16x8*)&W16[wo];
            const bf16x8 blo = *(const bf16x8*)&W16lo[wo];
            acc4[nt] = __builtin_amdgcn_mfma_f32_16x16x32_bf16(ahi[kc], bhi, acc4[nt], 0, 0, 0);
            acc4[nt] = __builtin_amdgcn_mfma_f32_16x16x32_bf16(alo[kc], bhi, acc4[nt], 0, 0, 0);
            acc4[nt] = __builtin_amdgcn_mfma_f32_16x16x32_bf16(ahi[kc], blo, acc4[nt], 0, 0, 0);
        }
    }

#pragma unroll
    for (int nt = 0; nt < 4; ++nt) {
        const float bv = bias[nt * 16 + r];
#pragma unroll
        for (int reg = 0; reg < 4; ++reg) {
            const int m = node0 + quad * 4 + reg;
            if (m < N_NODES) out[(size_t)m * 64 + nt * 16 + r] = acc4[nt][reg] + bv;
        }
    }
}

// ---------------------------------------------------------------------------
// Fallback path (R1): atomic scatter + shuffle finalize, if ws is too small.
// ---------------------------------------------------------------------------
__global__ __launch_bounds__(256) void fb_zero(float4* __restrict__ out4,
                                               float* __restrict__ deg) {
    const int stride = gridDim.x * blockDim.x;
    int i = blockIdx.x * blockDim.x + threadIdx.x;
    const int total4 = (N_NODES * D) / 4;
    for (int idx = i; idx < total4; idx += stride)
        out4[idx] = make_float4(0.f, 0.f, 0.f, 0.f);
    for (int idx = i; idx < N_NODES; idx += stride)
        deg[idx] = 0.f;
}

__global__ __launch_bounds__(256) void fb_scatter(
    const float* __restrict__ feat, const int* __restrict__ src,
    const int* __restrict__ dst, const float* __restrict__ ew,
    float* __restrict__ out, float* __restrict__ deg) {
    const int gid  = blockIdx.x * blockDim.x + threadIdx.x;
    const int e    = gid >> 6;
    const int lane = gid & 63;
    if (e >= N_EDGES) return;
    atomicAdd(&out[(size_t)dst[e] * D + lane], feat[(size_t)src[e] * D + lane] * ew[e]);
    if (lane == 0) atomicAdd(&deg[dst[e]], 1.0f);
}

__global__ __launch_bounds__(256) void fb_finalize(
    const float* __restrict__ feat, const float* __restrict__ Wn,
    const float* __restrict__ Ws, const float* __restrict__ bias,
    const float* __restrict__ deg, float* __restrict__ out) {
    __shared__ float lWn[D * 65];
    __shared__ float lWs[D * 65];
    for (int idx = threadIdx.x; idx < D * D; idx += 256) {
        const int r = idx >> 6, c = idx & 63;
        lWn[r * 65 + c] = Wn[idx];
        lWs[r * 65 + c] = Ws[idx];
    }
    __syncthreads();
    const int wave = threadIdx.x >> 6;
    const int lane = threadIdx.x & 63;
    const int n = blockIdx.x * 4 + wave;
    if (n >= N_NODES) return;
    const float f  = feat[(size_t)n * D + lane];
    const float sv = out[(size_t)n * D + lane];
    const float inv = 1.0f / fmaxf(deg[n], 1.0f);
    float acc_s = 0.f, acc_n = 0.f;
#pragma unroll
    for (int k = 0; k < D; ++k) {
        acc_s += __shfl(f, k)  * lWs[lane * 65 + k];
        acc_n += __shfl(sv, k) * lWn[lane * 65 + k];
    }
    out[(size_t)n * D + lane] = acc_s + acc_n * inv + bias[lane];
}

// ---------------------------------------------------------------------------
extern "C" void kernel_launch(void* const* d_in, const int* in_sizes, int n_in,
                              void* d_out, int out_size, void* d_ws, size_t ws_size,
                              hipStream_t stream) {
    const float* feat = (const float*)d_in[0];
    const int*   src  = (const int*)  d_in[1];
    const int*   dst  = (const int*)  d_in[2];
    const float* ew   = (const float*)d_in[3];
    const float* Wn   = (const float*)d_in[4];
    const float* Ws   = (const float*)d_in[5];
    const float* bias = (const float*)d_in[6];
    float* out = (float*)d_out;
    char* ws = (char*)d_ws;

    if (ws_size >= WS_NEEDED) {
        int* nstart   = (int*)(ws + OFF_NSTART);
        int* bincnt   = (int*)(ws + OFF_BINCNT);
        int* binstart = (int*)(ws + OFF_BINSTART);
        int* bincur   = (int*)(ws + OFF_BINCUR);
        unsigned short* W16    = (unsigned short*)(ws + OFF_W16);
        unsigned short* feat16 = (unsigned short*)(ws + OFF_FEAT16);
        uint2* entries2 = (uint2*)(ws + OFF_ENT2);
        uint2* entriesA = (uint2*)(ws + OFF_ENTA);

        k_zero     <<<1, 256, 0, stream>>>(bincnt);
        k_pre      <<<NCVT + NCNTB + 1, 256, 0, stream>>>((const float4*)feat, feat16,
                                                          Wn, Ws, W16, dst, bincnt);
        k_scan_bins<<<1, 128, 0, stream>>>(bincnt, binstart, bincur);
        k_place_a  <<<NPA, 256, 0, stream>>>(src, dst, ew, bincur, entriesA);
        k_sortbin  <<<NBINS, 1024, 0, stream>>>(binstart, entriesA, nstart, entries2);
        k_bucket   <<<NBUCK, 256, 0, stream>>>((const uint2*)feat16, feat, nstart,
                                               entries2, W16, bias, out);
    } else {
        float* deg = (float*)d_ws;
        fb_zero<<<2048, 256, 0, stream>>>((float4*)out, deg);
        fb_scatter<<<(N_EDGES * 64) / 256, 256, 0, stream>>>(feat, src, dst, ew, out, deg);
        fb_finalize<<<(N_NODES + 3) / 4, 256, 0, stream>>>(feat, Wn, Ws, bias, deg, out);
    }
}

// Round 11
// 240.444 us; speedup vs baseline: 2.5366x; 1.0250x over previous
//
#include <hip/hip_runtime.h>
#include <hip/hip_fp16.h>

// Problem constants (from reference)
constexpr int N_NODES = 100000;
constexpr int N_EDGES = 1600000;
constexpr int D = 64;          // D_IN == D_OUT == 64

// Bucketing: 32 consecutive dst nodes per bucket (one k_bucket block each).
// 100000 = 3125 * 32 exactly -> no padded nodes.
constexpr int BSH    = 5;
constexpr int BN     = 1 << BSH;                              // 32
constexpr int NBUCK  = N_NODES / BN;                          // 3125
constexpr int NN2    = N_NODES;                               // 100000 (exact)
constexpr int NCNTB  = 800;                                   // bin-hist blocks
constexpr int EPB2   = N_EDGES / NCNTB;                       // 2000 (exact)
constexpr int NCVT   = (N_NODES * D / 4) / 256;               // 6250 cvt blocks
constexpr int BINSH  = 9;                                     // 512-node coarse bins
constexpr int BINSZ  = 1 << BINSH;                            // 512
constexpr int NBINS  = (NN2 + BINSZ - 1) >> BINSH;            // 196
constexpr int CHUNK  = 2048;                                  // pass-A edges per block
constexpr int NPA    = (N_EDGES + CHUNK - 1) / CHUNK;         // 782 pass-A blocks

// ---------------------------------------------------------------------------
// Workspace layout (bytes). Total 40,034,816 <= 40,280,064 (verified avail).
// Two-pass binned counting sort; nstart built per-bin inside k_sortbin.
// ---------------------------------------------------------------------------
constexpr size_t OFF_NSTART   = 400384;                        // NN2+1 ints
constexpr size_t OFF_BINCNT   = 800768;                        // NBINS ints
constexpr size_t OFF_BINSTART = 801280;                        // NBINS+1 ints
constexpr size_t OFF_BINCUR   = 802304;                        // NBINS ints
constexpr size_t OFF_W16      = 1602048;                       // 32 KB (hi+lo planes)
constexpr size_t OFF_FEAT16   = 1634816;                       // N_NODES*64 fp16
constexpr size_t OFF_ENT2     = OFF_FEAT16 + (size_t)N_NODES * D * 2;  // 14,434,816
constexpr size_t OFF_ENTA     = OFF_ENT2 + (size_t)N_EDGES * 8;        // 27,234,816
constexpr size_t WS_NEEDED    = OFF_ENTA + (size_t)N_EDGES * 8;        // 40,034,816

typedef short  bf16x8 __attribute__((ext_vector_type(8)));
typedef float  f32x4  __attribute__((ext_vector_type(4)));

__device__ __forceinline__ unsigned short f2bf(float f) {   // RNE f32 -> bf16
    unsigned u = __float_as_uint(f);
    u += 0x7fffu + ((u >> 16) & 1u);
    return (unsigned short)(u >> 16);
}

// fp16 unpack helpers (gather path: 11-bit mantissa)
__device__ __forceinline__ float h2f_lo(unsigned u) {
    return __half2float(__ushort_as_half((unsigned short)(u & 0xFFFFu)));
}
__device__ __forceinline__ float h2f_hi(unsigned u) {
    return __half2float(__ushort_as_half((unsigned short)(u >> 16)));
}

// Split 8 consecutive f32 into hi/lo bf16 fragments (hi = RNE(f), lo = RNE(f - hi)).
__device__ __forceinline__ void split8(float4 p0, float4 p1, bf16x8& hi, bf16x8& lo) {
    float f[8] = {p0.x, p0.y, p0.z, p0.w, p1.x, p1.y, p1.z, p1.w};
#pragma unroll
    for (int i = 0; i < 8; ++i) {
        const unsigned short h = f2bf(f[i]);
        const float hf = __uint_as_float((unsigned)h << 16);
        hi[i] = (short)h;
        lo[i] = (short)f2bf(f[i] - hf);
    }
}

// ---------------------------------------------------------------------------
// K0: zero the per-bin counters (ws is poisoned before every launch).
// ---------------------------------------------------------------------------
__global__ __launch_bounds__(256) void k_zero(int* __restrict__ bincnt) {
    int i = blockIdx.x * 256 + threadIdx.x;
    if (i < NBINS) bincnt[i] = 0;
}

// ---------------------------------------------------------------------------
// K1 (fused): blocks [0,NCVT) convert feat f32->fp16; [NCVT,NCVT+NCNTB)
// LDS bin-level histogram (196 counters) -> global bincnt; last block builds
// combined W16 hi plane [j][k] (k<64=W_self, k>=64=W_neigh) AND lo plane.
// ---------------------------------------------------------------------------
__global__ __launch_bounds__(256) void k_pre(const float4* __restrict__ feat4,
                                             unsigned short* __restrict__ feat16,
                                             const float* __restrict__ Wn,
                                             const float* __restrict__ Ws,
                                             unsigned short* __restrict__ W16,
                                             const int* __restrict__ dst,
                                             int* __restrict__ bincnt) {
    __shared__ int l[NBINS];
    const int b   = blockIdx.x;
    const int tid = threadIdx.x;
    if (b < NCVT) {
        const int i = b * 256 + tid;
        float4 v = feat4[i];
        ushort4 o;
        o.x = __half_as_ushort(__float2half_rn(v.x));
        o.y = __half_as_ushort(__float2half_rn(v.y));
        o.z = __half_as_ushort(__float2half_rn(v.z));
        o.w = __half_as_ushort(__float2half_rn(v.w));
        *(ushort4*)&feat16[(size_t)i * 4] = o;
    } else if (b < NCVT + NCNTB) {
        for (int i = tid; i < NBINS; i += 256) l[i] = 0;
        __syncthreads();
        const int base = (b - NCVT) * EPB2;
        for (int k = tid; k < EPB2; k += 256)
            atomicAdd(&l[dst[base + k] >> BINSH], 1);
        __syncthreads();
        for (int i = tid; i < NBINS; i += 256)
            if (l[i]) atomicAdd(&bincnt[i], l[i]);
    } else {
        for (int e = tid; e < D * 128; e += 256) {
            const int j = e >> 7, k = e & 127;
            const float w = (k < D) ? Ws[j * D + k] : Wn[j * D + (k - D)];
            const unsigned short h = f2bf(w);
            const float hf = __uint_as_float((unsigned)h << 16);
            W16[e] = h;
            W16[D * 128 + e] = f2bf(w - hf);
        }
    }
}

// ---------------------------------------------------------------------------
// K2bin: exclusive scan of 196 bin counts -> binstart (+sentinel), bincur.
// ---------------------------------------------------------------------------
__global__ __launch_bounds__(256) void k_scan_bins(const int* __restrict__ bincnt,
                                                   int* __restrict__ binstart,
                                                   int* __restrict__ bincur) {
    __shared__ int s[256];
    const int t = threadIdx.x;
    const int v = (t < NBINS) ? bincnt[t] : 0;
    s[t] = v;
    __syncthreads();
    for (int off = 1; off < 256; off <<= 1) {
        int u = (t >= off) ? s[t - off] : 0;
        __syncthreads();
        s[t] += u;
        __syncthreads();
    }
    if (t < NBINS) { binstart[t] = s[t] - v; bincur[t] = s[t] - v; }
    if (t == 0) binstart[NBINS] = N_EDGES;
}

// ---------------------------------------------------------------------------
// K3a: pass A — LDS-staged partition of edges into 196 coarse bins (512 dst
// nodes each). entriesA.x = src | (dst&511)<<17 (src<2^17, 9 local bits).
// ---------------------------------------------------------------------------
__global__ __launch_bounds__(256) void k_place_a(const int* __restrict__ src,
                                                 const int* __restrict__ dst,
                                                 const float* __restrict__ ew,
                                                 int* __restrict__ bincur,
                                                 uint2* __restrict__ entriesA) {
    __shared__ __align__(16) uint2 stage[CHUNK];       // 16 KB
    __shared__ unsigned char sbin[CHUNK];              // 2 KB (bin < 196 fits)
    __shared__ int hist[NBINS], lstart[NBINS], lcur[NBINS], gbase[NBINS];
    __shared__ int s[256];
    const int tid = threadIdx.x;
    const int e0  = blockIdx.x * CHUNK;
    const int cnt = min(CHUNK, N_EDGES - e0);

    for (int i = tid; i < NBINS; i += 256) hist[i] = 0;
    __syncthreads();
    for (int k = tid; k < cnt; k += 256)
        atomicAdd(&hist[dst[e0 + k] >> BINSH], 1);
    __syncthreads();
    // block-local exclusive scan of 196 bin counts (256-wide Hillis-Steele)
    {
        const int v = (tid < NBINS) ? hist[tid] : 0;
        s[tid] = v;
        __syncthreads();
        for (int off = 1; off < 256; off <<= 1) {
            int u = (tid >= off) ? s[tid - off] : 0;
            __syncthreads();
            s[tid] += u;
            __syncthreads();
        }
        if (tid < NBINS) {
            const int ex = s[tid] - v;
            lstart[tid] = ex;
            lcur[tid]   = ex;
            gbase[tid]  = v ? atomicAdd(&bincur[tid], v) : 0;
        }
    }
    __syncthreads();
    // stage entries into LDS grouped by bin
    for (int k = tid; k < cnt; k += 256) {
        const int d = dst[e0 + k];
        const int b = d >> BINSH;
        const int p = atomicAdd(&lcur[b], 1);
        stage[p] = make_uint2((unsigned)src[e0 + k] | ((unsigned)(d & (BINSZ - 1)) << 17),
                              __float_as_uint(ew[e0 + k]));
        sbin[p]  = (unsigned char)b;
    }
    __syncthreads();
    // flush: consecutive slots -> consecutive global addresses per bin run
    for (int j = tid; j < cnt; j += 256) {
        const int b = sbin[j];
        entriesA[gbase[b] + (j - lstart[b])] = stage[j];
    }
}

// ---------------------------------------------------------------------------
// K3b (fused sort): one 1024-thread block per 512-node bin (196 blocks — 2x
// the machine fill of R10's 98). Histogram -> in-block scan -> nstart ->
// node-sorted placement. Bins contiguous in node- AND entry-space.
// ---------------------------------------------------------------------------
__global__ __launch_bounds__(1024) void k_sortbin(const int* __restrict__ binstart,
                                                  const uint2* __restrict__ entriesA,
                                                  int* __restrict__ nstart,
                                                  uint2* __restrict__ entries2) {
    __shared__ int h[BINSZ];
    __shared__ int sc[BINSZ];
    __shared__ int cur[BINSZ];
    const int tid = threadIdx.x;
    const int b   = blockIdx.x;
    const int s0  = binstart[b];
    const int cnt = binstart[b + 1] - s0;

    if (tid < BINSZ) h[tid] = 0;
    __syncthreads();
    for (int k = tid; k < cnt; k += 1024)
        atomicAdd(&h[entriesA[s0 + k].x >> 17], 1);
    __syncthreads();
    // in-block exclusive scan of the 512 per-node counts (first 512 threads)
    const int v = (tid < BINSZ) ? h[tid] : 0;
    if (tid < BINSZ) sc[tid] = v;
    __syncthreads();
    for (int off = 1; off < BINSZ; off <<= 1) {
        int u = 0;
        if (tid < BINSZ && tid >= off) u = sc[tid - off];
        __syncthreads();
        if (tid < BINSZ) sc[tid] += u;
        __syncthreads();
    }
    if (tid < BINSZ) {
        const int pos = s0 + sc[tid] - v;    // absolute start of this node's run
        cur[tid] = pos;
        const int n = (b << BINSH) + tid;
        if (n < NN2) nstart[n] = pos;
    }
    if (b == NBINS - 1 && tid == 0) nstart[NN2] = N_EDGES;
    __syncthreads();
    // place: bin slice is L2-warm from the histogram pass
    for (int k = tid; k < cnt; k += 1024) {
        const uint2 a = entriesA[s0 + k];
        const int p = atomicAdd(&cur[a.x >> 17], 1);
        entries2[p] = make_uint2(a.x & 0x1FFFFu, a.y);
    }
}

// ---------------------------------------------------------------------------
// K4 (aggregate + MFMA finalize). BN=32 -> 3125 blocks (12.2/CU vs R10's 6.1:
// the occupancy fix — R10 showed Occ 57%, TLP-starved latency stalls; deeper
// unroll did NOT help so unroll reverted to measured-best x2).
// P4: each wave aggregates 8 nodes. P5: each wave does 16 rows x 32 cols
// (2 nt tiles), waves split by (row-half, col-half). Numerics class unchanged.
// ---------------------------------------------------------------------------
__global__ __launch_bounds__(256, 8) void k_bucket(
    const uint2* __restrict__ feat16u2,
    const float* __restrict__ feat32,
    const int* __restrict__ nstart,
    const uint2* __restrict__ entries2,
    const unsigned short* __restrict__ W16,
    const float* __restrict__ bias,
    float* __restrict__ out) {
    __shared__ __align__(16) float aggrow[BN * 68];   // 8.7 KB f32
    __shared__ int hh[BN], st[BN];
    const int tid = threadIdx.x;
    const int b   = blockIdx.x;

    if (tid < BN) {
        const int s = nstart[b * BN + tid];
        const int e = nstart[b * BN + tid + 1];
        st[tid] = s;
        hh[tid] = e - s;
    }
    __syncthreads();

    // P4: aggregate — single acc, 4 lane-groups, stride 4, unroll x2.
    const int wave = tid >> 6, lane = tid & 63;
    const int group = lane >> 4, gl = lane & 15;
    for (int t = 0; t < 8; ++t) {
        const int dl  = wave * 8 + t;
        const int ss  = st[dl];
        const int deg = hh[dl];
        const int se  = ss + deg;
        float4 acc = make_float4(0.f, 0.f, 0.f, 0.f);
        int e = ss + group;
        for (; e + 4 < se; e += 8) {
            const uint2 en0 = entries2[e];
            const uint2 en1 = entries2[e + 4];
            const uint2 p0  = feat16u2[(size_t)en0.x * 16 + gl];
            const uint2 p1  = feat16u2[(size_t)en1.x * 16 + gl];
            const float w0  = __uint_as_float(en0.y);
            const float w1  = __uint_as_float(en1.y);
            acc.x = fmaf(h2f_lo(p0.x), w0, acc.x);
            acc.y = fmaf(h2f_hi(p0.x), w0, acc.y);
            acc.z = fmaf(h2f_lo(p0.y), w0, acc.z);
            acc.w = fmaf(h2f_hi(p0.y), w0, acc.w);
            acc.x = fmaf(h2f_lo(p1.x), w1, acc.x);
            acc.y = fmaf(h2f_hi(p1.x), w1, acc.y);
            acc.z = fmaf(h2f_lo(p1.y), w1, acc.z);
            acc.w = fmaf(h2f_hi(p1.y), w1, acc.w);
        }
        if (e < se) {
            const uint2 en = entries2[e];
            const float w  = __uint_as_float(en.y);
            const uint2 p  = feat16u2[(size_t)en.x * 16 + gl];
            acc.x = fmaf(h2f_lo(p.x), w, acc.x);
            acc.y = fmaf(h2f_hi(p.x), w, acc.y);
            acc.z = fmaf(h2f_lo(p.y), w, acc.z);
            acc.w = fmaf(h2f_hi(p.y), w, acc.w);
        }
#pragma unroll
        for (int m = 16; m <= 32; m <<= 1) {
            acc.x += __shfl_xor(acc.x, m);
            acc.y += __shfl_xor(acc.y, m);
            acc.z += __shfl_xor(acc.z, m);
            acc.w += __shfl_xor(acc.w, m);
        }
        if (group == 0) {
            const float inv = 1.0f / fmaxf((float)deg, 1.0f);
            float4 o = make_float4(acc.x * inv, acc.y * inv, acc.z * inv, acc.w * inv);
            *(float4*)&aggrow[dl * 68 + gl * 4] = o;
        }
    }
    __syncthreads();

    // P5: MFMA finalize with hi/lo split operands. Wave w: rows (w&1)*16,
    // cols (w>>1)*32 (2 nt tiles). Verified 16x16x32 C/D layout unchanged.
    const int quad = lane >> 4, r = lane & 15;
    const int rowh = wave & 1, colh = wave >> 1;
    const int node0 = b * BN + rowh * 16;
    int arow = node0 + r;
    if (arow > N_NODES - 1) arow = N_NODES - 1;

    bf16x8 ahi[4], alo[4];
    {
        const float* fp = &feat32[(size_t)arow * 64 + quad * 8];
        split8(*(const float4*)fp,        *(const float4*)(fp + 4),  ahi[0], alo[0]);
        split8(*(const float4*)(fp + 32), *(const float4*)(fp + 36), ahi[1], alo[1]);
        const float* ap = &aggrow[(rowh * 16 + r) * 68 + quad * 8];
        split8(*(const float4*)ap,        *(const float4*)(ap + 4),  ahi[2], alo[2]);
        split8(*(const float4*)(ap + 32), *(const float4*)(ap + 36), ahi[3], alo[3]);
    }

    const unsigned short* W16lo = W16 + D * 128;
    f32x4 acc4[2] = {};
#pragma unroll
    for (int nti = 0; nti < 2; ++nti) {
        const int nt = colh * 2 + nti;
#pragma unroll
        for (int kc = 0; kc < 4; ++kc) {
            const size_t wo = (size_t)(nt * 16 + r) * 128 + kc * 32 + quad * 8;
            const bf16x8 bhi = *(const bf16x8*)&W16[wo];
            const bf16x8 blo = *(const bf16x8*)&W16lo[wo];
            acc4[nti] = __builtin_amdgcn_mfma_f32_16x16x32_bf16(ahi[kc], bhi, acc4[nti], 0, 0, 0);
            acc4[nti] = __builtin_amdgcn_mfma_f32_16x16x32_bf16(alo[kc], bhi, acc4[nti], 0, 0, 0);
            acc4[nti] = __builtin_amdgcn_mfma_f32_16x16x32_bf16(ahi[kc], blo, acc4[nti], 0, 0, 0);
        }
    }

#pragma unroll
    for (int nti = 0; nti < 2; ++nti) {
        const int nt = colh * 2 + nti;
        const float bv = bias[nt * 16 + r];
#pragma unroll
        for (int reg = 0; reg < 4; ++reg) {
            const int m = node0 + quad * 4 + reg;
            if (m < N_NODES) out[(size_t)m * 64 + nt * 16 + r] = acc4[nti][reg] + bv;
        }
    }
}

// ---------------------------------------------------------------------------
// Fallback path (R1): atomic scatter + shuffle finalize, if ws is too small.
// ---------------------------------------------------------------------------
__global__ __launch_bounds__(256) void fb_zero(float4* __restrict__ out4,
                                               float* __restrict__ deg) {
    const int stride = gridDim.x * blockDim.x;
    int i = blockIdx.x * blockDim.x + threadIdx.x;
    const int total4 = (N_NODES * D) / 4;
    for (int idx = i; idx < total4; idx += stride)
        out4[idx] = make_float4(0.f, 0.f, 0.f, 0.f);
    for (int idx = i; idx < N_NODES; idx += stride)
        deg[idx] = 0.f;
}

__global__ __launch_bounds__(256) void fb_scatter(
    const float* __restrict__ feat, const int* __restrict__ src,
    const int* __restrict__ dst, const float* __restrict__ ew,
    float* __restrict__ out, float* __restrict__ deg) {
    const int gid  = blockIdx.x * blockDim.x + threadIdx.x;
    const int e    = gid >> 6;
    const int lane = gid & 63;
    if (e >= N_EDGES) return;
    atomicAdd(&out[(size_t)dst[e] * D + lane], feat[(size_t)src[e] * D + lane] * ew[e]);
    if (lane == 0) atomicAdd(&deg[dst[e]], 1.0f);
}

__global__ __launch_bounds__(256) void fb_finalize(
    const float* __restrict__ feat, const float* __restrict__ Wn,
    const float* __restrict__ Ws, const float* __restrict__ bias,
    const float* __restrict__ deg, float* __restrict__ out) {
    __shared__ float lWn[D * 65];
    __shared__ float lWs[D * 65];
    for (int idx = threadIdx.x; idx < D * D; idx += 256) {
        const int r = idx >> 6, c = idx & 63;
        lWn[r * 65 + c] = Wn[idx];
        lWs[r * 65 + c] = Ws[idx];
    }
    __syncthreads();
    const int wave = threadIdx.x >> 6;
    const int lane = threadIdx.x & 63;
    const int n = blockIdx.x * 4 + wave;
    if (n >= N_NODES) return;
    const float f  = feat[(size_t)n * D + lane];
    const float sv = out[(size_t)n * D + lane];
    const float inv = 1.0f / fmaxf(deg[n], 1.0f);
    float acc_s = 0.f, acc_n = 0.f;
#pragma unroll
    for (int k = 0; k < D; ++k) {
        acc_s += __shfl(f, k)  * lWs[lane * 65 + k];
        acc_n += __shfl(sv, k) * lWn[lane * 65 + k];
    }
    out[(size_t)n * D + lane] = acc_s + acc_n * inv + bias[lane];
}

// ---------------------------------------------------------------------------
extern "C" void kernel_launch(void* const* d_in, const int* in_sizes, int n_in,
                              void* d_out, int out_size, void* d_ws, size_t ws_size,
                              hipStream_t stream) {
    const float* feat = (const float*)d_in[0];
    const int*   src  = (const int*)  d_in[1];
    const int*   dst  = (const int*)  d_in[2];
    const float* ew   = (const float*)d_in[3];
    const float* Wn   = (const float*)d_in[4];
    const float* Ws   = (const float*)d_in[5];
    const float* bias = (const float*)d_in[6];
    float* out = (float*)d_out;
    char* ws = (char*)d_ws;

    if (ws_size >= WS_NEEDED) {
        int* nstart   = (int*)(ws + OFF_NSTART);
        int* bincnt   = (int*)(ws + OFF_BINCNT);
        int* binstart = (int*)(ws + OFF_BINSTART);
        int* bincur   = (int*)(ws + OFF_BINCUR);
        unsigned short* W16    = (unsigned short*)(ws + OFF_W16);
        unsigned short* feat16 = (unsigned short*)(ws + OFF_FEAT16);
        uint2* entries2 = (uint2*)(ws + OFF_ENT2);
        uint2* entriesA = (uint2*)(ws + OFF_ENTA);

        k_zero     <<<1, 256, 0, stream>>>(bincnt);
        k_pre      <<<NCVT + NCNTB + 1, 256, 0, stream>>>((const float4*)feat, feat16,
                                                          Wn, Ws, W16, dst, bincnt);
        k_scan_bins<<<1, 256, 0, stream>>>(bincnt, binstart, bincur);
        k_place_a  <<<NPA, 256, 0, stream>>>(src, dst, ew, bincur, entriesA);
        k_sortbin  <<<NBINS, 1024, 0, stream>>>(binstart, entriesA, nstart, entries2);
        k_bucket   <<<NBUCK, 256, 0, stream>>>((const uint2*)feat16, feat, nstart,
                                               entries2, W16, bias, out);
    } else {
        float* deg = (float*)d_ws;
        fb_zero<<<2048, 256, 0, stream>>>((float4*)out, deg);
        fb_scatter<<<(N_EDGES * 64) / 256, 256, 0, stream>>>(feat, src, dst, ew, out, deg);
        fb_finalize<<<(N_NODES + 3) / 4, 256, 0, stream>>>(feat, Wn, Ws, bias, deg, out);
    }
}